// Round 13
// baseline (411.799 us; speedup 1.0000x reference)
//
#include <hip/hip_runtime.h>

#define DEVI __device__ __forceinline__

typedef unsigned short u16;
typedef __attribute__((ext_vector_type(8))) short bf8v;   // 8 bf16 = 4 VGPR
typedef __attribute__((ext_vector_type(4))) short s4v;    // 4 bf16
typedef __attribute__((ext_vector_type(4))) float f4v;    // MFMA acc

constexpr int NB = 4, C = 128, H = 96, W = 96, HW = H * W;   // 9216
constexpr int HL = 48, WL = 48, HWL = HL * WL;               // 2304
constexpr int CODES = 1024, DIM = 128;
constexpr int ROWS = NB * HWL;                               // 9216 VQ rows

DEVI float lrelu_f(float v) { return v >= 0.f ? v : 0.2f * v; }

DEVI u16 f2bf(float f) {  // RNE float->bf16
  union { float f; unsigned u; } v; v.f = f;
  unsigned r = (v.u + 0x7FFFu + ((v.u >> 16) & 1u)) >> 16;
  return (u16)r;
}

DEVI void wave_red2(float& s, float& s2) {
#pragma unroll
  for (int o = 32; o > 0; o >>= 1) { s += __shfl_down(s, o); s2 += __shfl_down(s2, o); }
}

DEVI bool block_red2(float& s, float& s2) {
  wave_red2(s, s2);
  __shared__ float ls[8], ls2[8];
  int wv = threadIdx.x >> 6, ln = threadIdx.x & 63;
  if (ln == 0) { ls[wv] = s; ls2[wv] = s2; }
  __syncthreads();
  if (threadIdx.x == 0) {
    s = ls[0] + ls[1] + ls[2] + ls[3];
    s2 = ls2[0] + ls2[1] + ls2[2] + ls2[3];
    return true;
  }
  return false;
}

// ---------------- stats reduction: 8 slots, PER partials each ----------------
__global__ __launch_bounds__(256) void k_red16(const float2* __restrict__ src,
                                               float* __restrict__ dst, int per) {
  int slot = blockIdx.x;
  float s = 0.f, s2 = 0.f;
  for (int i = threadIdx.x; i < per; i += 256) {
    float2 v = src[(size_t)slot * per + i];
    s += v.x; s2 += v.y;
  }
  if (block_red2(s, s2)) { dst[slot * 2] = s; dst[slot * 2 + 1] = s2; }
}

// ---------------- unified pre-pack: d1w | d0w | pjw | emb | embnorm ----------------
__global__ __launch_bounds__(256) void k_pack_all(
    const float* __restrict__ d1_w, const float* __restrict__ d0_w,
    const float* __restrict__ pj_w, const float* __restrict__ emb,
    u16* __restrict__ A1, u16* __restrict__ A0, u16* __restrict__ Apj,
    float4* __restrict__ embp, float* __restrict__ enorm) {
  int b = blockIdx.x, t = threadIdx.x;
  if (b < 1152) {                                  // d1: A1[ky][ch8][kx][co128][ci32]
    int i = b * 256 + t;
    int ci = i & 31, co = (i >> 5) & 127, r = i >> 12;
    int kx = r % 3; int r2 = r / 3; int ch = r2 & 7, ky = r2 >> 3;
    A1[i] = f2bf(d1_w[((size_t)(co * 256 + ch * 32 + ci) * 3 + ky) * 3 + kx]);
  } else if (b < 1728) {                           // d0: A0[wy][ch4][wx][co128][ci32]
    int i = (b - 1152) * 256 + t;
    int ci = i & 31, co = (i >> 5) & 127, r = i >> 12;
    int wx = r % 3; int r2 = r / 3; int ch = r2 & 3, wy = r2 >> 2;
    A0[i] = f2bf(d0_w[((size_t)((ch * 32 + ci) * 128 + co) * 3 + wy) * 3 + wx]);
  } else if (b < 1792) {                           // pj: Apj[ch4][co128][ci32]
    int i = (b - 1728) * 256 + t;
    int ci = i & 31, co = (i >> 5) & 127, ch = i >> 12;
    Apj[i] = f2bf(pj_w[co * 128 + ch * 32 + ci]);
  } else if (b < 1920) {                           // emb pack: embp[k4][code]
    int i = (b - 1792) * 256 + t;
    int k4 = i & 31, code = i >> 5;
    embp[(size_t)k4 * 1024 + code] = *(const float4*)&emb[(size_t)code * DIM + k4 * 4];
  } else {                                         // emb row norms (4 blocks)
    int e = (b - 1920) * 256 + t;
    const float4* p = (const float4*)(emb + (size_t)e * DIM);
    float s = 0.f;
#pragma unroll 8
    for (int i = 0; i < 32; ++i) {
      float4 v = p[i];
      s = fmaf(v.x, v.x, s); s = fmaf(v.y, v.y, s); s = fmaf(v.z, v.z, s); s = fmaf(v.w, v.w, s);
    }
    enorm[e] = s;
  }
}

// ---------------- conv e0 tiled: 3x3, Cin=4, s=1, p=1; block = (n,co,16 rows) ----------------
__global__ __launch_bounds__(256) void k_conv_e0t(
    const float* __restrict__ x, const float* __restrict__ wg,
    const float* __restrict__ bias, float* __restrict__ out, float2* __restrict__ ps) {
  __shared__ float xs[4][18][104];
  int b = blockIdx.x;
  int rq = b % 6; int co = (b / 6) & 127; int n = b / 768;
  int t = threadIdx.x;
  int tx = t & 15, r = t >> 4;
  int y0 = rq * 16;
  for (int e = t; e < 4 * 18 * 104; e += 256) {
    int ci = e / 1872; int rem = e - ci * 1872;
    int row = rem / 104; int off = rem - row * 104;
    int iy = y0 - 1 + row; int ix = off - 1;
    float v = 0.f;
    if ((unsigned)iy < 96u && (unsigned)ix < 96u)
      v = x[((size_t)(n * 4 + ci)) * HW + iy * 96 + ix];
    xs[ci][row][off] = v;
  }
  float wr[4][9];
  const float* wp = wg + co * 36;
#pragma unroll
  for (int ci = 0; ci < 4; ++ci)
#pragma unroll
    for (int k = 0; k < 9; ++k) wr[ci][k] = wp[ci * 9 + k];
  float bv = bias[co];
  __syncthreads();
  float acc[6];
#pragma unroll
  for (int p = 0; p < 6; ++p) acc[p] = bv;
#pragma unroll
  for (int ci = 0; ci < 4; ++ci) {
#pragma unroll
    for (int ky = 0; ky < 3; ++ky) {
      const float* rp = &xs[ci][r + ky][6 * tx];
      float f[8];
#pragma unroll
      for (int j = 0; j < 4; ++j) {
        float2 v2 = *(const float2*)(rp + 2 * j);
        f[2 * j] = v2.x; f[2 * j + 1] = v2.y;
      }
      float w0 = wr[ci][ky * 3 + 0], w1 = wr[ci][ky * 3 + 1], w2 = wr[ci][ky * 3 + 2];
#pragma unroll
      for (int p = 0; p < 6; ++p)
        acc[p] = fmaf(w0, f[p], fmaf(w1, f[p + 1], fmaf(w2, f[p + 2], acc[p])));
    }
  }
  float* op = out + ((size_t)(n * 128 + co) * 96 + (y0 + r)) * 96 + 6 * tx;
#pragma unroll
  for (int j = 0; j < 3; ++j) {
    float2 v2 = { acc[2 * j], acc[2 * j + 1] };
    *(float2*)(op + 2 * j) = v2;
  }
  float s = 0.f, s2 = 0.f;
#pragma unroll
  for (int p = 0; p < 6; ++p) { s += acc[p]; s2 += acc[p] * acc[p]; }
  if (block_red2(s, s2)) {
    int slot = n * 2 + (co >> 6);
    ps[(size_t)slot * 384 + (co & 63) * 6 + rq] = make_float2(s, s2);
  }
}

// ---------------- GN(e0)+lrelu into padded fp32 buffer gnpad[n][c][98][100] ----------------
__global__ __launch_bounds__(256) void k_gn_pad(
    const float* __restrict__ in, const float* __restrict__ stats,
    const float* __restrict__ gam, const float* __restrict__ bet, float* __restrict__ outp) {
  int idx = blockIdx.x * 256 + threadIdx.x;        // 512*9800 = 5017600
  int col = idx % 100; int r2 = idx / 100; int row = r2 % 98; int c2 = r2 / 98;
  int c = c2 & 127; int n = c2 >> 7;
  float v = 0.f;
  if (row >= 1 && row <= 96 && col >= 1 && col <= 96) {
    const float* st = stats + (n * 2 + (c >> 6)) * 2;
    const float invc = 1.f / (64.f * 9216.f);
    float mu = st[0] * invc;
    float var = fmaf(-mu, mu, st[1] * invc);
    float rs = rsqrtf(var + 1e-5f);
    float raw = in[(size_t)c2 * 9216 + (row - 1) * 96 + (col - 1)];
    v = lrelu_f(fmaf((raw - mu) * rs, gam[c], bet[c]));
  }
  outp[idx] = v;
}

// ---------------- GN + lrelu, NHWC fp32 -> bf16 (d0 layer) ----------------
__global__ __launch_bounds__(256) void k_gn_nhwc_bf(
    const float* __restrict__ in, u16* __restrict__ outb, const float* __restrict__ stats,
    const float* __restrict__ gam, const float* __restrict__ bet) {
  int idx = blockIdx.x * 256 + threadIdx.x;
  int c = idx & 127;
  int n = idx / (9216 * 128);
  const float* st = stats + (n * 2 + (c >> 6)) * 2;
  const float invcnt = 1.f / (64.f * 9216.f);
  float mu = st[0] * invcnt;
  float var = fmaf(-mu, mu, st[1] * invcnt);
  float rs = rsqrtf(var + 1e-5f);
  float v = in[idx];
  outb[idx] = f2bf(lrelu_f(fmaf((v - mu) * rs, gam[c], bet[c])));
}

// ---------------- e1 split-K(4) fp32 from gnpad: 3x3, Cin=128, stride 2 ----------------
// grid: cb(2:64co) x kb(4:32ci) x rq(24:2rows) x n(4) = 768 blocks
// thread: tx(16) x r(2) x cg(8) -> 8 co x 1 row x 3 px (px = tx+16p)
__global__ __launch_bounds__(256, 4) void k_conv_e1s(
    const float* __restrict__ gnpad, const float* __restrict__ wg, float* __restrict__ part) {
  __shared__ float insh[8 * 500];     // [ci8][row5][100 stride] 16 KB
  __shared__ float wsh[8 * 576];      // [ci8][k9][co64] 18.4 KB
  int b = blockIdx.x;
  int cb = b & 1; int kb = (b >> 1) & 3; int rq = (b >> 3) % 24; int n = b / 192;
  int co0 = cb * 64;
  int t = threadIdx.x;
  int tx = t & 15, r = (t >> 4) & 1, cg = t >> 5;
  float acc[8][3];
#pragma unroll
  for (int c = 0; c < 8; ++c)
#pragma unroll
    for (int p = 0; p < 3; ++p) acc[c][p] = 0.f;
  for (int cc = 0; cc < 4; ++cc) {
    __syncthreads();
    const float4* src = (const float4*)(gnpad + ((size_t)(n * 128 + kb * 32 + cc * 8)) * 9800 + 4 * rq * 100);
#pragma unroll
    for (int j = 0; j < 4; ++j) {
      int e = t + j * 256;
      if (e < 1000) {
        int ci = e / 125; int q = e - ci * 125;
        *(float4*)&insh[ci * 500 + q * 4] = src[(size_t)ci * 2450 + q];
      }
    }
#pragma unroll
    for (int j = 0; j < 18; ++j) {
      int e = t + j * 256;
      int ci = e / 576; int rem = e - ci * 576; int k = rem >> 6; int co = rem & 63;
      wsh[e] = wg[(size_t)(co0 + co) * 1152 + (kb * 32 + cc * 8 + ci) * 9 + k];
    }
    __syncthreads();
#pragma unroll
    for (int ci = 0; ci < 8; ++ci) {
      float iv[3][3][3];
      int ib = ci * 500 + (2 * r) * 100 + 2 * tx;
#pragma unroll
      for (int ky = 0; ky < 3; ++ky) {
#pragma unroll
        for (int p = 0; p < 3; ++p) {
          int a = ib + ky * 100 + 32 * p;
          float2 v2 = *(const float2*)&insh[a];
          iv[ky][p][0] = v2.x; iv[ky][p][1] = v2.y; iv[ky][p][2] = insh[a + 2];
        }
      }
#pragma unroll
      for (int k = 0; k < 9; ++k) {
        float4 wa = *(const float4*)&wsh[ci * 576 + k * 64 + cg * 8];
        float4 wb = *(const float4*)&wsh[ci * 576 + k * 64 + cg * 8 + 4];
        int ky = k / 3, kx = k - ky * 3;
#pragma unroll
        for (int p = 0; p < 3; ++p) {
          float ivv = iv[ky][p][kx];
          acc[0][p] = fmaf(wa.x, ivv, acc[0][p]);
          acc[1][p] = fmaf(wa.y, ivv, acc[1][p]);
          acc[2][p] = fmaf(wa.z, ivv, acc[2][p]);
          acc[3][p] = fmaf(wa.w, ivv, acc[3][p]);
          acc[4][p] = fmaf(wb.x, ivv, acc[4][p]);
          acc[5][p] = fmaf(wb.y, ivv, acc[5][p]);
          acc[6][p] = fmaf(wb.z, ivv, acc[6][p]);
          acc[7][p] = fmaf(wb.w, ivv, acc[7][p]);
        }
      }
    }
  }
  int oy = 2 * rq + r;
#pragma unroll
  for (int c = 0; c < 8; ++c) {
    size_t ob = (size_t)kb * 1179648 + ((size_t)(n * 128 + co0 + cg * 8 + c)) * HWL + oy * 48 + tx;
#pragma unroll
    for (int p = 0; p < 3; ++p) part[ob + 16 * p] = acc[c][p];
  }
}

// ---------------- e1 combine ----------------
__global__ __launch_bounds__(256) void k_e1comb(
    const float* __restrict__ part, const float* __restrict__ bias,
    float* __restrict__ latent, float2* __restrict__ ps) {
  int idx = blockIdx.x * 256 + threadIdx.x;
  int c = (idx / HWL) & 127;
  int n = idx / (HWL * 128);
  float v = part[idx] + part[idx + 1179648] + part[idx + 2 * 1179648] + part[idx + 3 * 1179648] + bias[c];
  latent[idx] = v;
  float s = v, s2 = v * v;
  if (block_red2(s, s2)) {
    int slot = n * 2 + (c >> 6);
    int j = blockIdx.x % 9;
    ps[(size_t)slot * 576 + (c & 63) * 9 + j] = make_float2(s, s2);
  }
}

// ---------------- pv 1x1 conv fp32, fused e1-GN ----------------
__global__ __launch_bounds__(256, 2) void k_pv(
    const float* __restrict__ in, const float* __restrict__ w,
    const float* __restrict__ bias, const float* __restrict__ stats1,
    const float* __restrict__ gam, const float* __restrict__ bet,
    float* __restrict__ out) {
  int b = blockIdx.x;
  int pxb = b % 9; int cb = (b / 9) & 1; int n = b / 18;
  int t = threadIdx.x;
  int pxg = t & 31, cg = t >> 5;
  int px0 = pxb * 256 + pxg * 8;
  int cobase = cb * 64 + cg * 8;
  const float invc = 1.f / (64.f * 2304.f);
  float acc[8][8];
#pragma unroll
  for (int c = 0; c < 8; ++c) {
    float bv = bias[cobase + c];
#pragma unroll
    for (int p = 0; p < 8; ++p) acc[c][p] = bv;
  }
  const float* ipb = in + (size_t)n * 128 * HWL + px0;
  for (int ci0 = 0; ci0 < 128; ci0 += 4) {
    float inr[4][8];
#pragma unroll
    for (int i = 0; i < 4; ++i) {
      int c = ci0 + i;
      const float* st = stats1 + (n * 2 + (c >> 6)) * 2;
      float mu = st[0] * invc;
      float var = fmaf(-mu, mu, st[1] * invc);
      float rsv = rsqrtf(var + 1e-5f);
      float ga = gam[c], be = bet[c];
      const float* ip = ipb + (size_t)c * HWL;
      float4 a = *(const float4*)ip; float4 bq = *(const float4*)(ip + 4);
      inr[i][0] = lrelu_f(fmaf((a.x - mu) * rsv, ga, be));
      inr[i][1] = lrelu_f(fmaf((a.y - mu) * rsv, ga, be));
      inr[i][2] = lrelu_f(fmaf((a.z - mu) * rsv, ga, be));
      inr[i][3] = lrelu_f(fmaf((a.w - mu) * rsv, ga, be));
      inr[i][4] = lrelu_f(fmaf((bq.x - mu) * rsv, ga, be));
      inr[i][5] = lrelu_f(fmaf((bq.y - mu) * rsv, ga, be));
      inr[i][6] = lrelu_f(fmaf((bq.z - mu) * rsv, ga, be));
      inr[i][7] = lrelu_f(fmaf((bq.w - mu) * rsv, ga, be));
    }
    float wr[8][4];
#pragma unroll
    for (int c = 0; c < 8; ++c) {
      float4 wv = *(const float4*)&w[(size_t)(cobase + c) * 128 + ci0];
      wr[c][0] = wv.x; wr[c][1] = wv.y; wr[c][2] = wv.z; wr[c][3] = wv.w;
    }
#pragma unroll
    for (int i = 0; i < 4; ++i)
#pragma unroll
      for (int c = 0; c < 8; ++c)
#pragma unroll
        for (int p = 0; p < 8; ++p) acc[c][p] = fmaf(wr[c][i], inr[i][p], acc[c][p]);
  }
#pragma unroll
  for (int c = 0; c < 8; ++c) {
    float* op = out + (size_t)(n * 128 + cobase + c) * HWL + px0;
    float4 v0 = { acc[c][0], acc[c][1], acc[c][2], acc[c][3] };
    float4 v1 = { acc[c][4], acc[c][5], acc[c][6], acc[c][7] };
    *(float4*)op = v0; *(float4*)(op + 4) = v1;
  }
}

// ---------------- VQ: fp32 distances, 16 rows/block + top-3 ----------------
__global__ __launch_bounds__(256) void k_vq(
    const float* __restrict__ z, const float4* __restrict__ embp,
    const float* __restrict__ emb, const float* __restrict__ enorm,
    u16* __restrict__ qb, float* __restrict__ counts, float* __restrict__ pvq) {
  __shared__ float zs[16][DIM];      // 8 KB
  __shared__ float sd[16][CODES];    // 64 KB
  __shared__ float lred[4];
  int r0 = blockIdx.x * 16;
  for (int q = threadIdx.x; q < 16 * DIM; q += 256) {
    int i = q >> 7, c = q & 127;
    int r = r0 + i; int n = r / HWL, p = r % HWL;
    zs[i][c] = z[(size_t)(n * C + c) * HWL + p];
  }
  __syncthreads();
  float acc[4][16];
#pragma unroll
  for (int k = 0; k < 4; ++k)
#pragma unroll
    for (int i = 0; i < 16; ++i) acc[k][i] = 0.f;
  int t = threadIdx.x;
  for (int c4 = 0; c4 < 32; ++c4) {
    const float4* ep = embp + (size_t)c4 * 1024;
    float4 e0 = ep[t], e1 = ep[t + 256], e2 = ep[t + 512], e3 = ep[t + 768];
#pragma unroll
    for (int i = 0; i < 16; ++i) {
      float4 zv = *(const float4*)(&zs[i][c4 * 4]);
      acc[0][i] = fmaf(zv.x, e0.x, fmaf(zv.y, e0.y, fmaf(zv.z, e0.z, fmaf(zv.w, e0.w, acc[0][i]))));
      acc[1][i] = fmaf(zv.x, e1.x, fmaf(zv.y, e1.y, fmaf(zv.z, e1.z, fmaf(zv.w, e1.w, acc[1][i]))));
      acc[2][i] = fmaf(zv.x, e2.x, fmaf(zv.y, e2.y, fmaf(zv.z, e2.z, fmaf(zv.w, e2.w, acc[2][i]))));
      acc[3][i] = fmaf(zv.x, e3.x, fmaf(zv.y, e3.y, fmaf(zv.z, e3.z, fmaf(zv.w, e3.w, acc[3][i]))));
    }
  }
#pragma unroll
  for (int k = 0; k < 4; ++k) {
    int e = t + k * 256;
    float nv = enorm[e];
#pragma unroll
    for (int i = 0; i < 16; ++i) sd[i][e] = fmaf(-2.f, acc[k][i], nv);
  }
  __syncthreads();
  int wv = threadIdx.x >> 6, ln = threadIdx.x & 63;
  float lpw = 0.f;
  for (int i = wv * 4; i < wv * 4 + 4; ++i) {
    int f0 = -1, f1 = -1; int idxs[3];
#pragma unroll
    for (int pass = 0; pass < 3; ++pass) {
      float bvv = 3.4e38f; int bi = CODES;
      for (int k = 0; k < 16; ++k) {
        int e = ln + k * 64;
        float v = sd[i][e];
        bool skip = (e == f0) || (e == f1);
        if (!skip && v < bvv) { bvv = v; bi = e; }
      }
#pragma unroll
      for (int o = 32; o > 0; o >>= 1) {
        float ov = __shfl_down(bvv, o); int oi = __shfl_down(bi, o);
        if (ov < bvv || (ov == bvv && oi < bi)) { bvv = ov; bi = oi; }
      }
      bi = __shfl(bi, 0);
      idxs[pass] = bi;
      if (pass == 0) f0 = bi; else if (pass == 1) f1 = bi;
    }
    int r = r0 + i;
    const float* q0 = emb + (size_t)idxs[0] * DIM;
    float lp = 0.f;
    for (int c = ln; c < DIM; c += 64) {
      float qv = q0[c];
      qb[(size_t)r * 128 + c] = f2bf(qv);
      float d = zs[i][c] - qv;
      lp = fmaf(d, d, lp);
    }
#pragma unroll
    for (int o = 32; o > 0; o >>= 1) lp += __shfl_down(lp, o);
    if (ln == 0) { lpw += lp; atomicAdd(&counts[idxs[2]], 1.f); }
  }
  if (ln == 0) lred[wv] = lpw;
  __syncthreads();
  if (threadIdx.x == 0) pvq[blockIdx.x] = lred[0] + lred[1] + lred[2] + lred[3];
}

// ---------------- finalize ----------------
__global__ __launch_bounds__(256) void k_finalize(
    const float* __restrict__ counts, const float* __restrict__ pvq, float* __restrict__ out) {
  float local = 0.f;
#pragma unroll
  for (int k = 0; k < 4; ++k) {
    float cnt = counts[threadIdx.x + k * 256];
    float pr = cnt * (1.f / (float)ROWS);
    local = fmaf(pr, logf(pr + 1e-10f), local);
  }
  float lsum = 0.f;
  for (int i = threadIdx.x; i < ROWS / 16; i += 256) lsum += pvq[i];
  if (block_red2(local, lsum)) {
    out[1 + NB * 4 * HW] = expf(-local);
    out[0] = 0.25f * lsum * (1.f / (9216.f * 128.f));
  }
}

// ---------------- proj (1x1) MFMA, fused e0-GN on staged enc1 ----------------
__global__ __launch_bounds__(256) void k_proj_m(
    const float* __restrict__ enc1, const u16* __restrict__ Apj,
    const float* __restrict__ bias, const float* __restrict__ stats0,
    const float* __restrict__ gam, const float* __restrict__ bet,
    u16* __restrict__ skipb) {
  __shared__ u16 Ash[128 * 32];
  __shared__ u16 Bsh[96 * 32];
  int b = blockIdx.x; int rowi = b % 96; int n = b / 96; int px0 = rowi * 96;
  int t = threadIdx.x; int w = t >> 6; int lane = t & 63;
  int ln16 = lane & 15, quad = lane >> 4;
  int co0w = (w & 1) * 64; int pxh = (w >> 1) * 48;
  int c_l = t & 31, xg = t >> 5;
  const float invc = 1.f / (64.f * 9216.f);
  f4v acc[4][3];
#pragma unroll
  for (int mt = 0; mt < 4; ++mt)
#pragma unroll
    for (int nt = 0; nt < 3; ++nt) acc[mt][nt] = (f4v){0.f, 0.f, 0.f, 0.f};
  for (int ch = 0; ch < 4; ++ch) {
    __syncthreads();
#pragma unroll
    for (int e = 0; e < 2; ++e) {
      int i = t + e * 256;
      *(bf8v*)&Ash[i * 8] = *(const bf8v*)&Apj[ch * 4096 + i * 8];
    }
    int c = ch * 32 + c_l;
    const float* st = stats0 + (n * 2 + (ch >> 1)) * 2;
    float mu = st[0] * invc;
    float var = fmaf(-mu, mu, st[1] * invc);
    float rsv = rsqrtf(var + 1e-5f);
    float ga = gam[c], be = bet[c];
    const float* ip = enc1 + (size_t)(n * 128 + c) * 9216 + px0 + xg * 12;
#pragma unroll
    for (int j4 = 0; j4 < 3; ++j4) {
      float4 v = *(const float4*)(ip + j4 * 4);
      int pxb = xg * 12 + j4 * 4;
      Bsh[(pxb + 0) * 32 + c_l] = f2bf(lrelu_f(fmaf((v.x - mu) * rsv, ga, be)));
      Bsh[(pxb + 1) * 32 + c_l] = f2bf(lrelu_f(fmaf((v.y - mu) * rsv, ga, be)));
      Bsh[(pxb + 2) * 32 + c_l] = f2bf(lrelu_f(fmaf((v.z - mu) * rsv, ga, be)));
      Bsh[(pxb + 3) * 32 + c_l] = f2bf(lrelu_f(fmaf((v.w - mu) * rsv, ga, be)));
    }
    __syncthreads();
    bf8v af[4];
#pragma unroll
    for (int mt = 0; mt < 4; ++mt)
      af[mt] = *(const bf8v*)&Ash[(co0w + mt * 16 + ln16) * 32 + quad * 8];
#pragma unroll
    for (int nt = 0; nt < 3; ++nt) {
      bf8v bfv = *(const bf8v*)&Bsh[(pxh + nt * 16 + ln16) * 32 + quad * 8];
#pragma unroll
      for (int mt = 0; mt < 4; ++mt)
        acc[mt][nt] = __builtin_amdgcn_mfma_f32_16x16x32_bf16(af[mt], bfv, acc[mt][nt], 0, 0, 0);
    }
  }
#pragma unroll
  for (int mt = 0; mt < 4; ++mt) {
    int co = co0w + mt * 16 + quad * 4;
    float4 bv = *(const float4*)&bias[co];
#pragma unroll
    for (int nt = 0; nt < 3; ++nt) {
      int px = px0 + pxh + nt * 16 + ln16;
      u16* dp = skipb + (size_t)(n * 9216 + px) * 128 + co;
      s4v sv;
      sv.x = (short)f2bf(acc[mt][nt].x + bv.x);
      sv.y = (short)f2bf(acc[mt][nt].y + bv.y);
      sv.z = (short)f2bf(acc[mt][nt].z + bv.z);
      sv.w = (short)f2bf(acc[mt][nt].w + bv.w);
      *(s4v*)dp = sv;
    }
  }
}

// ---------------- d0 conv-transpose MFMA ----------------
__global__ __launch_bounds__(256) void k_convt_d0m(
    const u16* __restrict__ qb, const u16* __restrict__ A0,
    const float* __restrict__ bias, float* __restrict__ h, float2* __restrict__ ps) {
  __shared__ u16 Ash[2 * 128 * 32];
  __shared__ u16 Bsh[49 * 32];
  int b = blockIdx.x; int rx = b & 1; int oy = (b >> 1) % 96; int n = b / 192;
  int t = threadIdx.x; int w = t >> 6; int lane = t & 63;
  int ln16 = lane & 15, quad = lane >> 4;
  int co0w = w * 32;
  f4v acc[2][3];
#pragma unroll
  for (int mt = 0; mt < 2; ++mt)
#pragma unroll
    for (int nt = 0; nt < 3; ++nt) acc[mt][nt] = (f4v){0.f, 0.f, 0.f, 0.f};
  int nyt, wys[2], iys[2];
  if (oy & 1) {
    wys[0] = 2; iys[0] = (oy - 1) >> 1;
    wys[1] = 0; iys[1] = (oy + 1) >> 1;
    nyt = (iys[1] < 48) ? 2 : 1;
  } else { wys[0] = 1; iys[0] = oy >> 1; wys[1] = 0; iys[1] = 0; nyt = 1; }
  int nxt = rx ? 2 : 1;
  int wxs[2], xof[2];
  if (rx) { wxs[0] = 2; xof[0] = 0; wxs[1] = 0; xof[1] = 1; }
  else { wxs[0] = 1; xof[0] = 0; wxs[1] = 0; xof[1] = 0; }
  for (int yt = 0; yt < nyt; ++yt) {
    for (int ch = 0; ch < 4; ++ch) {
      __syncthreads();
      for (int e = t; e < nxt * 512; e += 256) {
        int xt = e >> 9, e2 = e & 511;
        const u16* Asrc = A0 + (size_t)(((wys[yt] * 4 + ch) * 3 + wxs[xt]) * 4096);
        *(bf8v*)&Ash[xt * 4096 + e2 * 8] = *(const bf8v*)&Asrc[e2 * 8];
      }
      const u16* bbase = qb + (size_t)(n * 2304 + iys[yt] * 48) * 128 + ch * 32;
      for (int e = t; e < 196; e += 256) {
        int row = e >> 2, seg = e & 3;
        bf8v v = {0, 0, 0, 0, 0, 0, 0, 0};
        if (row < 48) v = *(const bf8v*)&bbase[row * 128 + seg * 8];
        *(bf8v*)&Bsh[row * 32 + seg * 8] = v;
      }
      __syncthreads();
      for (int xt = 0; xt < nxt; ++xt) {
        bf8v af[2];
#pragma unroll
        for (int mt = 0; mt < 2; ++mt)
          af[mt] = *(const bf8v*)&Ash[xt * 4096 + (co0w + mt * 16 + ln16) * 32 + quad * 8];
#pragma unroll
        for (int nt = 0; nt < 3; ++nt) {
          bf8v bfv = *(const bf8v*)&Bsh[(nt * 16 + ln16 + xof[xt]) * 32 + quad * 8];
#pragma unroll
          for (int mt = 0; mt < 2; ++mt)
            acc[mt][nt] = __builtin_amdgcn_mfma_f32_16x16x32_bf16(af[mt], bfv, acc[mt][nt], 0, 0, 0);
        }
      }
    }
  }
  float s = 0.f, s2 = 0.f;
#pragma unroll
  for (int mt = 0; mt < 2; ++mt) {
    int co = co0w + mt * 16 + quad * 4;
    float4 bv = *(const float4*)&bias[co];
#pragma unroll
    for (int nt = 0; nt < 3; ++nt) {
      int px = nt * 16 + ln16;
      int ox = 2 * px + rx;
      float4 v;
      v.x = acc[mt][nt].x + bv.x; v.y = acc[mt][nt].y + bv.y;
      v.z = acc[mt][nt].z + bv.z; v.w = acc[mt][nt].w + bv.w;
      *(float4*)(h + (size_t)(n * 9216 + oy * 96 + ox) * 128 + co) = v;
      s += v.x + v.y + v.z + v.w;
      s2 += v.x * v.x + v.y * v.y + v.z * v.z + v.w * v.w;
    }
  }
  wave_red2(s, s2);
  if (lane == 0) {
    int slot = n * 2 + (w >> 1);
    ps[(size_t)slot * 384 + (oy * 2 + rx) * 2 + (w & 1)] = make_float2(s, s2);
  }
}

// ---------------- d1 conv MFMA ----------------
__global__ __launch_bounds__(256) void k_conv_d1m(
    const u16* __restrict__ hb, const u16* __restrict__ sb,
    const u16* __restrict__ A1, const float* __restrict__ bias,
    float* __restrict__ y, float2* __restrict__ ps) {
  __shared__ u16 Ash[3 * 128 * 32];
  __shared__ u16 Bsh[98 * 32];
  int b = blockIdx.x; int oy = b % 96; int n = b / 96;
  int t = threadIdx.x; int w = t >> 6; int lane = t & 63;
  int ln16 = lane & 15, quad = lane >> 4;
  int co0w = (w & 1) * 64; int pxh = (w >> 1) * 48;
  f4v acc[4][3];
#pragma unroll
  for (int mt = 0; mt < 4; ++mt)
#pragma unroll
    for (int nt = 0; nt < 3; ++nt) acc[mt][nt] = (f4v){0.f, 0.f, 0.f, 0.f};
  int ky0 = (oy == 0) ? 1 : 0, ky1 = (oy == 95) ? 1 : 2;
  for (int ky = ky0; ky <= ky1; ++ky) {
    int iy = oy + ky - 1;
    for (int ch = 0; ch < 8; ++ch) {
      const u16* src = (ch < 4) ? hb : sb;
      int c0 = (ch & 3) * 32;
      const u16* Asrc = A1 + (size_t)(ky * 8 + ch) * 12288;
      const u16* bbase = src + (size_t)(n * 9216 + iy * 96) * 128 + c0;
      __syncthreads();
#pragma unroll
      for (int e = 0; e < 6; ++e) {
        int i = t + e * 256;
        *(bf8v*)&Ash[i * 8] = *(const bf8v*)&Asrc[i * 8];
      }
      for (int e = t; e < 392; e += 256) {
        int row = e >> 2, seg = e & 3;
        int ix = row - 1;
        bf8v v = {0, 0, 0, 0, 0, 0, 0, 0};
        if ((unsigned)ix < 96u) v = *(const bf8v*)&bbase[ix * 128 + seg * 8];
        *(bf8v*)&Bsh[row * 32 + seg * 8] = v;
      }
      __syncthreads();
#pragma unroll
      for (int kx = 0; kx < 3; ++kx) {
        bf8v af[4];
#pragma unroll
        for (int mt = 0; mt < 4; ++mt)
          af[mt] = *(const bf8v*)&Ash[(kx * 128 + co0w + mt * 16 + ln16) * 32 + quad * 8];
#pragma unroll
        for (int nt = 0; nt < 3; ++nt) {
          bf8v bfv = *(const bf8v*)&Bsh[(pxh + nt * 16 + ln16 + kx) * 32 + quad * 8];
#pragma unroll
          for (int mt = 0; mt < 4; ++mt)
            acc[mt][nt] = __builtin_amdgcn_mfma_f32_16x16x32_bf16(af[mt], bfv, acc[mt][nt], 0, 0, 0);
        }
      }
    }
  }
  float s = 0.f, s2 = 0.f;
#pragma unroll
  for (int mt = 0; mt < 4; ++mt) {
    int co = co0w + mt * 16 + quad * 4;
    float4 bv = *(const float4*)&bias[co];
#pragma unroll
    for (int nt = 0; nt < 3; ++nt) {
      int px = pxh + nt * 16 + ln16;
      float4 v;
      v.x = acc[mt][nt].x + bv.x; v.y = acc[mt][nt].y + bv.y;
      v.z = acc[mt][nt].z + bv.z; v.w = acc[mt][nt].w + bv.w;
      *(float4*)(y + (size_t)(n * 9216 + oy * 96 + px) * 128 + co) = v;
      s += v.x + v.y + v.z + v.w;
      s2 += v.x * v.x + v.y * v.y + v.z * v.z + v.w * v.w;
    }
  }
  wave_red2(s, s2);
  if (lane == 0) {
    int slot = n * 2 + (w & 1);
    ps[(size_t)slot * 192 + oy * 2 + (w >> 1)] = make_float2(s, s2);
  }
}

// ---------------- readout, fused d1-GN: out(NCHW) = ro_w x GN(y NHWC fp32) ----------------
__global__ __launch_bounds__(256) void k_ro(
    const float* __restrict__ y, const float* __restrict__ w,
    const float* __restrict__ bias, const float* __restrict__ stats3,
    const float* __restrict__ gam, const float* __restrict__ bet,
    float* __restrict__ out) {
  __shared__ float wsh[512];
  __shared__ float gsh[128], bsh[128];
  __shared__ float red[64][16];
  int b = blockIdx.x; int n = b / 144; int px0 = (b % 144) * 64;
  int t = threadIdx.x; int q = t & 3, pxl = t >> 2;
  for (int e = t; e < 512; e += 256) wsh[e] = w[e];
  if (t < 128) { gsh[t] = gam[t]; bsh[t] = bet[t]; }
  __syncthreads();
  const float invc = 1.f / (64.f * 9216.f);
  int g = q >> 1;
  const float* st = stats3 + (n * 2 + g) * 2;
  float mu = st[0] * invc;
  float var = fmaf(-mu, mu, st[1] * invc);
  float rsv = rsqrtf(var + 1e-5f);
  const float* yb = y + (size_t)(n * 9216 + px0 + pxl) * 128 + q * 32;
  float s0 = 0.f, s1 = 0.f, s2 = 0.f, s3 = 0.f;
#pragma unroll
  for (int j = 0; j < 8; ++j) {
    float4 v = *(const float4*)(yb + j * 4);
    int c0 = q * 32 + j * 4;
    float vx = lrelu_f(fmaf((v.x - mu) * rsv, gsh[c0 + 0], bsh[c0 + 0]));
    float vy = lrelu_f(fmaf((v.y - mu) * rsv, gsh[c0 + 1], bsh[c0 + 1]));
    float vz = lrelu_f(fmaf((v.z - mu) * rsv, gsh[c0 + 2], bsh[c0 + 2]));
    float vw = lrelu_f(fmaf((v.w - mu) * rsv, gsh[c0 + 3], bsh[c0 + 3]));
    const float* w0 = &wsh[0 * 128 + c0];
    const float* w1 = &wsh[1 * 128 + c0];
    const float* w2 = &wsh[2 * 128 + c0];
    const float* w3 = &wsh[3 * 128 + c0];
    s0 += vx * w0[0] + vy * w0[1] + vz * w0[2] + vw * w0[3];
    s1 += vx * w1[0] + vy * w1[1] + vz * w1[2] + vw * w1[3];
    s2 += vx * w2[0] + vy * w2[1] + vz * w2[2] + vw * w2[3];
    s3 += vx * w3[0] + vy * w3[1] + vz * w3[2] + vw * w3[3];
  }
  red[pxl][q * 4 + 0] = s0; red[pxl][q * 4 + 1] = s1;
  red[pxl][q * 4 + 2] = s2; red[pxl][q * 4 + 3] = s3;
  __syncthreads();
  float val = red[pxl][0 * 4 + q] + red[pxl][1 * 4 + q] + red[pxl][2 * 4 + q] + red[pxl][3 * 4 + q] + bias[q];
  out[1 + (size_t)(n * 4 + q) * 9216 + px0 + pxl] = val;
}

extern "C" void kernel_launch(void* const* d_in, const int* in_sizes, int n_in,
                              void* d_out, int out_size, void* d_ws, size_t ws_size,
                              hipStream_t stream) {
  (void)in_sizes; (void)n_in; (void)out_size; (void)ws_size;
  const float* x     = (const float*)d_in[0];
  const float* e0_w  = (const float*)d_in[1];
  const float* e0_b  = (const float*)d_in[2];
  const float* e0_g  = (const float*)d_in[3];
  const float* e0_bt = (const float*)d_in[4];
  const float* e1_w  = (const float*)d_in[5];
  const float* e1_b  = (const float*)d_in[6];
  const float* e1_g  = (const float*)d_in[7];
  const float* e1_bt = (const float*)d_in[8];
  const float* pv_w  = (const float*)d_in[9];
  const float* pv_b  = (const float*)d_in[10];
  const float* emb   = (const float*)d_in[11];
  const float* d0_w  = (const float*)d_in[12];
  const float* d0_b  = (const float*)d_in[13];
  const float* d0_g  = (const float*)d_in[14];
  const float* d0_bt = (const float*)d_in[15];
  const float* d1_w  = (const float*)d_in[16];
  const float* d1_b  = (const float*)d_in[17];
  const float* d1_g  = (const float*)d_in[18];
  const float* d1_bt = (const float*)d_in[19];
  const float* pj_w  = (const float*)d_in[20];
  const float* pj_b  = (const float*)d_in[21];
  const float* ro_w  = (const float*)d_in[22];
  const float* ro_b  = (const float*)d_in[23];
  float* out = (float*)d_out;
  float* ws = (float*)d_ws;

  float* stats  = ws;                       // 64
  float* counts = ws + 64;                  // 1024
  float* enorm  = ws + 1088;                // 1024
  float* pvq    = ws + 2112;                // 1152
  float2* ps_e0 = (float2*)(ws + 3264);
  float2* ps_e1 = (float2*)(ws + 76992);
  float2* ps_d0 = (float2*)(ws + 95424);
  float2* ps_d1 = (float2*)(ws + 107712);
  float* enc1   = ws + 114688;                     // 4718592 fp32 NCHW (raw e0 out)
  float* latent = enc1 + (size_t)NB * C * HW;      // 1179648 fp32 NCHW (raw e1 out)
  float* zbuf   = latent + (size_t)NB * C * HWL;   // 1179648 fp32 NCHW
  float* hy     = zbuf + (size_t)NB * C * HWL;     // 4718592 fp32 (e1 4-slice partials; then h,y NHWC)
  u16* qb    = (u16*)(hy + (size_t)NB * C * HW);   // 1179648 bf16 NHWC
  u16* hb    = qb + (size_t)NB * C * HWL;          // 4718592 bf16 NHWC
  u16* skipb = hb + (size_t)NB * C * HW;           // 4718592 bf16 NHWC
  u16* A1    = skipb + (size_t)NB * C * HW;        // 294912
  u16* A0    = A1 + 294912;                        // 147456
  u16* Apj   = A0 + 147456;                        // 16384
  float4* embp = (float4*)(Apj + 16384 + 64);      // 32768 float4
  // gnpad (20.07 MB) aliases qb+hb+skipb (21.2 MB); liveness: gn_pad -> e1s,
  // then k_vq/proj_m/gn_nhwc_bf overwrite. Keeps ws at the proven ~70 MB.
  float* gnpad = (float*)qb;

  hipMemsetAsync(counts, 0, 1024 * sizeof(float), stream);

  k_pack_all<<<1924, 256, 0, stream>>>(d1_w, d0_w, pj_w, emb, A1, A0, Apj, embp, enorm);

  k_conv_e0t<<<3072, 256, 0, stream>>>(x, e0_w, e0_b, enc1, ps_e0);
  k_red16<<<8, 256, 0, stream>>>(ps_e0, stats + 0, 384);
  k_gn_pad<<<512 * 9800 / 256, 256, 0, stream>>>(enc1, stats + 0, e0_g, e0_bt, gnpad);
  k_conv_e1s<<<768, 256, 0, stream>>>(gnpad, e1_w, hy);
  k_e1comb<<<NB * C * HWL / 256, 256, 0, stream>>>(hy, e1_b, latent, ps_e1);
  k_red16<<<8, 256, 0, stream>>>(ps_e1, stats + 16, 576);
  k_pv<<<NB * 2 * 9, 256, 0, stream>>>(latent, pv_w, pv_b, stats + 16, e1_g, e1_bt, zbuf);
  k_vq<<<ROWS / 16, 256, 0, stream>>>(zbuf, embp, emb, enorm, qb, counts, pvq);
  k_finalize<<<1, 256, 0, stream>>>(counts, pvq, out);

  k_proj_m<<<NB * 96, 256, 0, stream>>>(enc1, Apj, pj_b, stats + 0, e0_g, e0_bt, skipb);
  k_convt_d0m<<<NB * 96 * 2, 256, 0, stream>>>(qb, A0, d0_b, hy, ps_d0);
  k_red16<<<8, 256, 0, stream>>>(ps_d0, stats + 32, 384);
  k_gn_nhwc_bf<<<NB * C * HW / 256, 256, 0, stream>>>(hy, hb, stats + 32, d0_g, d0_bt);
  k_conv_d1m<<<NB * 96, 256, 0, stream>>>(hb, skipb, A1, d1_b, hy, ps_d1);
  k_red16<<<8, 256, 0, stream>>>(ps_d1, stats + 48, 192);
  k_ro<<<NB * 144, 256, 0, stream>>>(hy, ro_w, ro_b, stats + 48, d1_g, d1_bt, out);
}

// Round 14
// 394.856 us; speedup vs baseline: 1.0429x; 1.0429x over previous
//
#include <hip/hip_runtime.h>

#define DEVI __device__ __forceinline__

typedef unsigned short u16;
typedef __attribute__((ext_vector_type(8))) short bf8v;   // 8 bf16 = 4 VGPR
typedef __attribute__((ext_vector_type(4))) short s4v;    // 4 bf16
typedef __attribute__((ext_vector_type(4))) float f4v;    // MFMA acc

constexpr int NB = 4, C = 128, H = 96, W = 96, HW = H * W;   // 9216
constexpr int HL = 48, WL = 48, HWL = HL * WL;               // 2304
constexpr int CODES = 1024, DIM = 128;
constexpr int ROWS = NB * HWL;                               // 9216 VQ rows

DEVI float lrelu_f(float v) { return v >= 0.f ? v : 0.2f * v; }

DEVI u16 f2bf(float f) {  // RNE float->bf16
  union { float f; unsigned u; } v; v.f = f;
  unsigned r = (v.u + 0x7FFFu + ((v.u >> 16) & 1u)) >> 16;
  return (u16)r;
}

DEVI void wave_red2(float& s, float& s2) {
#pragma unroll
  for (int o = 32; o > 0; o >>= 1) { s += __shfl_down(s, o); s2 += __shfl_down(s2, o); }
}

DEVI bool block_red2(float& s, float& s2) {
  wave_red2(s, s2);
  __shared__ float ls[8], ls2[8];
  int wv = threadIdx.x >> 6, ln = threadIdx.x & 63;
  if (ln == 0) { ls[wv] = s; ls2[wv] = s2; }
  __syncthreads();
  if (threadIdx.x == 0) {
    s = ls[0] + ls[1] + ls[2] + ls[3];
    s2 = ls2[0] + ls2[1] + ls2[2] + ls2[3];
    return true;
  }
  return false;
}

// ---------------- stats reduction: 8 slots, PER partials each ----------------
__global__ __launch_bounds__(256) void k_red16(const float2* __restrict__ src,
                                               float* __restrict__ dst, int per) {
  int slot = blockIdx.x;
  float s = 0.f, s2 = 0.f;
  for (int i = threadIdx.x; i < per; i += 256) {
    float2 v = src[(size_t)slot * per + i];
    s += v.x; s2 += v.y;
  }
  if (block_red2(s, s2)) { dst[slot * 2] = s; dst[slot * 2 + 1] = s2; }
}

// ---------------- unified pre-pack: d1w | d0w | pjw | emb | embnorm ----------------
__global__ __launch_bounds__(256) void k_pack_all(
    const float* __restrict__ d1_w, const float* __restrict__ d0_w,
    const float* __restrict__ pj_w, const float* __restrict__ emb,
    u16* __restrict__ A1, u16* __restrict__ A0, u16* __restrict__ Apj,
    float4* __restrict__ embp, float* __restrict__ enorm) {
  int b = blockIdx.x, t = threadIdx.x;
  if (b < 1152) {                                  // d1: A1[ky][ch8][kx][co128][ci32]
    int i = b * 256 + t;
    int ci = i & 31, co = (i >> 5) & 127, r = i >> 12;
    int kx = r % 3; int r2 = r / 3; int ch = r2 & 7, ky = r2 >> 3;
    A1[i] = f2bf(d1_w[((size_t)(co * 256 + ch * 32 + ci) * 3 + ky) * 3 + kx]);
  } else if (b < 1728) {                           // d0: A0[wy][ch4][wx][co128][ci32]
    int i = (b - 1152) * 256 + t;
    int ci = i & 31, co = (i >> 5) & 127, r = i >> 12;
    int wx = r % 3; int r2 = r / 3; int ch = r2 & 3, wy = r2 >> 2;
    A0[i] = f2bf(d0_w[((size_t)((ch * 32 + ci) * 128 + co) * 3 + wy) * 3 + wx]);
  } else if (b < 1792) {                           // pj: Apj[ch4][co128][ci32]
    int i = (b - 1728) * 256 + t;
    int ci = i & 31, co = (i >> 5) & 127, ch = i >> 12;
    Apj[i] = f2bf(pj_w[co * 128 + ch * 32 + ci]);
  } else if (b < 1920) {                           // emb pack: embp[k4][code]
    int i = (b - 1792) * 256 + t;
    int k4 = i & 31, code = i >> 5;
    embp[(size_t)k4 * 1024 + code] = *(const float4*)&emb[(size_t)code * DIM + k4 * 4];
  } else {                                         // emb row norms (4 blocks)
    int e = (b - 1920) * 256 + t;
    const float4* p = (const float4*)(emb + (size_t)e * DIM);
    float s = 0.f;
#pragma unroll 8
    for (int i = 0; i < 32; ++i) {
      float4 v = p[i];
      s = fmaf(v.x, v.x, s); s = fmaf(v.y, v.y, s); s = fmaf(v.z, v.z, s); s = fmaf(v.w, v.w, s);
    }
    enorm[e] = s;
  }
}

// ---------------- conv e0 tiled: 3x3, Cin=4, s=1, p=1; block = (n,co,16 rows) ----------------
__global__ __launch_bounds__(256) void k_conv_e0t(
    const float* __restrict__ x, const float* __restrict__ wg,
    const float* __restrict__ bias, float* __restrict__ out, float2* __restrict__ ps) {
  __shared__ float xs[4][18][104];
  int b = blockIdx.x;
  int rq = b % 6; int co = (b / 6) & 127; int n = b / 768;
  int t = threadIdx.x;
  int tx = t & 15, r = t >> 4;
  int y0 = rq * 16;
  for (int e = t; e < 4 * 18 * 104; e += 256) {
    int ci = e / 1872; int rem = e - ci * 1872;
    int row = rem / 104; int off = rem - row * 104;
    int iy = y0 - 1 + row; int ix = off - 1;
    float v = 0.f;
    if ((unsigned)iy < 96u && (unsigned)ix < 96u)
      v = x[((size_t)(n * 4 + ci)) * HW + iy * 96 + ix];
    xs[ci][row][off] = v;
  }
  float wr[4][9];
  const float* wp = wg + co * 36;
#pragma unroll
  for (int ci = 0; ci < 4; ++ci)
#pragma unroll
    for (int k = 0; k < 9; ++k) wr[ci][k] = wp[ci * 9 + k];
  float bv = bias[co];
  __syncthreads();
  float acc[6];
#pragma unroll
  for (int p = 0; p < 6; ++p) acc[p] = bv;
#pragma unroll
  for (int ci = 0; ci < 4; ++ci) {
#pragma unroll
    for (int ky = 0; ky < 3; ++ky) {
      const float* rp = &xs[ci][r + ky][6 * tx];
      float f[8];
#pragma unroll
      for (int j = 0; j < 4; ++j) {
        float2 v2 = *(const float2*)(rp + 2 * j);
        f[2 * j] = v2.x; f[2 * j + 1] = v2.y;
      }
      float w0 = wr[ci][ky * 3 + 0], w1 = wr[ci][ky * 3 + 1], w2 = wr[ci][ky * 3 + 2];
#pragma unroll
      for (int p = 0; p < 6; ++p)
        acc[p] = fmaf(w0, f[p], fmaf(w1, f[p + 1], fmaf(w2, f[p + 2], acc[p])));
    }
  }
  float* op = out + ((size_t)(n * 128 + co) * 96 + (y0 + r)) * 96 + 6 * tx;
#pragma unroll
  for (int j = 0; j < 3; ++j) {
    float2 v2 = { acc[2 * j], acc[2 * j + 1] };
    *(float2*)(op + 2 * j) = v2;
  }
  float s = 0.f, s2 = 0.f;
#pragma unroll
  for (int p = 0; p < 6; ++p) { s += acc[p]; s2 += acc[p] * acc[p]; }
  if (block_red2(s, s2)) {
    int slot = n * 2 + (co >> 6);
    ps[(size_t)slot * 384 + (co & 63) * 6 + rq] = make_float2(s, s2);
  }
}

// ---------------- GN(e0)+lrelu into padded fp32 buffer gnpad[n][c][98][100] ----------------
__global__ __launch_bounds__(256) void k_gn_pad(
    const float* __restrict__ in, const float* __restrict__ stats,
    const float* __restrict__ gam, const float* __restrict__ bet, float* __restrict__ outp) {
  int idx = blockIdx.x * 256 + threadIdx.x;        // 512*9800 = 5017600
  int col = idx % 100; int r2 = idx / 100; int row = r2 % 98; int c2 = r2 / 98;
  int c = c2 & 127; int n = c2 >> 7;
  float v = 0.f;
  if (row >= 1 && row <= 96 && col >= 1 && col <= 96) {
    const float* st = stats + (n * 2 + (c >> 6)) * 2;
    const float invc = 1.f / (64.f * 9216.f);
    float mu = st[0] * invc;
    float var = fmaf(-mu, mu, st[1] * invc);
    float rs = rsqrtf(var + 1e-5f);
    float raw = in[(size_t)c2 * 9216 + (row - 1) * 96 + (col - 1)];
    v = lrelu_f(fmaf((raw - mu) * rs, gam[c], bet[c]));
  }
  outp[idx] = v;
}

// ---------------- GN + lrelu, NHWC fp32 -> bf16 (d0 layer) ----------------
__global__ __launch_bounds__(256) void k_gn_nhwc_bf(
    const float* __restrict__ in, u16* __restrict__ outb, const float* __restrict__ stats,
    const float* __restrict__ gam, const float* __restrict__ bet) {
  int idx = blockIdx.x * 256 + threadIdx.x;
  int c = idx & 127;
  int n = idx / (9216 * 128);
  const float* st = stats + (n * 2 + (c >> 6)) * 2;
  const float invcnt = 1.f / (64.f * 9216.f);
  float mu = st[0] * invcnt;
  float var = fmaf(-mu, mu, st[1] * invcnt);
  float rs = rsqrtf(var + 1e-5f);
  float v = in[idx];
  outb[idx] = f2bf(lrelu_f(fmaf((v - mu) * rs, gam[c], bet[c])));
}

// ---------------- e1 split-K(4) fp32 from gnpad: 3x3, Cin=128, stride 2 ----------------
// grid: cb(2:64co) x kb(4:32ci) x rq(24:2rows) x n(4) = 768 blocks
// thread: tx(16) x r(2) x cg(8) -> 8 co x 1 row x 3 px (px = tx+16p)
__global__ __launch_bounds__(256, 4) void k_conv_e1s(
    const float* __restrict__ gnpad, const float* __restrict__ wg, float* __restrict__ part) {
  __shared__ float insh[8 * 500];     // [ci8][row5][100 stride] 16 KB
  __shared__ float wsh[8 * 576];      // [ci8][k9][co64] 18.4 KB
  int b = blockIdx.x;
  int cb = b & 1; int kb = (b >> 1) & 3; int rq = (b >> 3) % 24; int n = b / 192;
  int co0 = cb * 64;
  int t = threadIdx.x;
  int tx = t & 15, r = (t >> 4) & 1, cg = t >> 5;
  float acc[8][3];
#pragma unroll
  for (int c = 0; c < 8; ++c)
#pragma unroll
    for (int p = 0; p < 3; ++p) acc[c][p] = 0.f;
  for (int cc = 0; cc < 4; ++cc) {
    __syncthreads();
    const float4* src = (const float4*)(gnpad + ((size_t)(n * 128 + kb * 32 + cc * 8)) * 9800 + 4 * rq * 100);
#pragma unroll
    for (int j = 0; j < 4; ++j) {
      int e = t + j * 256;
      if (e < 1000) {
        int ci = e / 125; int q = e - ci * 125;
        *(float4*)&insh[ci * 500 + q * 4] = src[(size_t)ci * 2450 + q];
      }
    }
#pragma unroll
    for (int j = 0; j < 18; ++j) {
      int e = t + j * 256;
      int ci = e / 576; int rem = e - ci * 576; int k = rem >> 6; int co = rem & 63;
      wsh[e] = wg[(size_t)(co0 + co) * 1152 + (kb * 32 + cc * 8 + ci) * 9 + k];
    }
    __syncthreads();
#pragma unroll
    for (int ci = 0; ci < 8; ++ci) {
      float iv[3][3][3];
      int ib = ci * 500 + (2 * r) * 100 + 2 * tx;
#pragma unroll
      for (int ky = 0; ky < 3; ++ky) {
#pragma unroll
        for (int p = 0; p < 3; ++p) {
          int a = ib + ky * 100 + 32 * p;
          float2 v2 = *(const float2*)&insh[a];
          iv[ky][p][0] = v2.x; iv[ky][p][1] = v2.y; iv[ky][p][2] = insh[a + 2];
        }
      }
#pragma unroll
      for (int k = 0; k < 9; ++k) {
        float4 wa = *(const float4*)&wsh[ci * 576 + k * 64 + cg * 8];
        float4 wb = *(const float4*)&wsh[ci * 576 + k * 64 + cg * 8 + 4];
        int ky = k / 3, kx = k - ky * 3;
#pragma unroll
        for (int p = 0; p < 3; ++p) {
          float ivv = iv[ky][p][kx];
          acc[0][p] = fmaf(wa.x, ivv, acc[0][p]);
          acc[1][p] = fmaf(wa.y, ivv, acc[1][p]);
          acc[2][p] = fmaf(wa.z, ivv, acc[2][p]);
          acc[3][p] = fmaf(wa.w, ivv, acc[3][p]);
          acc[4][p] = fmaf(wb.x, ivv, acc[4][p]);
          acc[5][p] = fmaf(wb.y, ivv, acc[5][p]);
          acc[6][p] = fmaf(wb.z, ivv, acc[6][p]);
          acc[7][p] = fmaf(wb.w, ivv, acc[7][p]);
        }
      }
    }
  }
  int oy = 2 * rq + r;
#pragma unroll
  for (int c = 0; c < 8; ++c) {
    size_t ob = (size_t)kb * 1179648 + ((size_t)(n * 128 + co0 + cg * 8 + c)) * HWL + oy * 48 + tx;
#pragma unroll
    for (int p = 0; p < 3; ++p) part[ob + 16 * p] = acc[c][p];
  }
}

// ---------------- e1 combine ----------------
__global__ __launch_bounds__(256) void k_e1comb(
    const float* __restrict__ part, const float* __restrict__ bias,
    float* __restrict__ latent, float2* __restrict__ ps) {
  int idx = blockIdx.x * 256 + threadIdx.x;
  int c = (idx / HWL) & 127;
  int n = idx / (HWL * 128);
  float v = part[idx] + part[idx + 1179648] + part[idx + 2 * 1179648] + part[idx + 3 * 1179648] + bias[c];
  latent[idx] = v;
  float s = v, s2 = v * v;
  if (block_red2(s, s2)) {
    int slot = n * 2 + (c >> 6);
    int j = blockIdx.x % 9;
    ps[(size_t)slot * 576 + (c & 63) * 9 + j] = make_float2(s, s2);
  }
}

// ---------------- pv 1x1 conv fp32, fused e1-GN ----------------
__global__ __launch_bounds__(256, 2) void k_pv(
    const float* __restrict__ in, const float* __restrict__ w,
    const float* __restrict__ bias, const float* __restrict__ stats1,
    const float* __restrict__ gam, const float* __restrict__ bet,
    float* __restrict__ out) {
  int b = blockIdx.x;
  int pxb = b % 9; int cb = (b / 9) & 1; int n = b / 18;
  int t = threadIdx.x;
  int pxg = t & 31, cg = t >> 5;
  int px0 = pxb * 256 + pxg * 8;
  int cobase = cb * 64 + cg * 8;
  const float invc = 1.f / (64.f * 2304.f);
  float acc[8][8];
#pragma unroll
  for (int c = 0; c < 8; ++c) {
    float bv = bias[cobase + c];
#pragma unroll
    for (int p = 0; p < 8; ++p) acc[c][p] = bv;
  }
  const float* ipb = in + (size_t)n * 128 * HWL + px0;
  for (int ci0 = 0; ci0 < 128; ci0 += 4) {
    float inr[4][8];
#pragma unroll
    for (int i = 0; i < 4; ++i) {
      int c = ci0 + i;
      const float* st = stats1 + (n * 2 + (c >> 6)) * 2;
      float mu = st[0] * invc;
      float var = fmaf(-mu, mu, st[1] * invc);
      float rsv = rsqrtf(var + 1e-5f);
      float ga = gam[c], be = bet[c];
      const float* ip = ipb + (size_t)c * HWL;
      float4 a = *(const float4*)ip; float4 bq = *(const float4*)(ip + 4);
      inr[i][0] = lrelu_f(fmaf((a.x - mu) * rsv, ga, be));
      inr[i][1] = lrelu_f(fmaf((a.y - mu) * rsv, ga, be));
      inr[i][2] = lrelu_f(fmaf((a.z - mu) * rsv, ga, be));
      inr[i][3] = lrelu_f(fmaf((a.w - mu) * rsv, ga, be));
      inr[i][4] = lrelu_f(fmaf((bq.x - mu) * rsv, ga, be));
      inr[i][5] = lrelu_f(fmaf((bq.y - mu) * rsv, ga, be));
      inr[i][6] = lrelu_f(fmaf((bq.z - mu) * rsv, ga, be));
      inr[i][7] = lrelu_f(fmaf((bq.w - mu) * rsv, ga, be));
    }
    float wr[8][4];
#pragma unroll
    for (int c = 0; c < 8; ++c) {
      float4 wv = *(const float4*)&w[(size_t)(cobase + c) * 128 + ci0];
      wr[c][0] = wv.x; wr[c][1] = wv.y; wr[c][2] = wv.z; wr[c][3] = wv.w;
    }
#pragma unroll
    for (int i = 0; i < 4; ++i)
#pragma unroll
      for (int c = 0; c < 8; ++c)
#pragma unroll
        for (int p = 0; p < 8; ++p) acc[c][p] = fmaf(wr[c][i], inr[i][p], acc[c][p]);
  }
#pragma unroll
  for (int c = 0; c < 8; ++c) {
    float* op = out + (size_t)(n * 128 + cobase + c) * HWL + px0;
    float4 v0 = { acc[c][0], acc[c][1], acc[c][2], acc[c][3] };
    float4 v1 = { acc[c][4], acc[c][5], acc[c][6], acc[c][7] };
    *(float4*)op = v0; *(float4*)(op + 4) = v1;
  }
}

// ---------------- VQ: fp32 distances (coalesced embp) + top-3 (R11 version) ----------------
__global__ __launch_bounds__(256) void k_vq(
    const float* __restrict__ z, const float4* __restrict__ embp,
    const float* __restrict__ emb, const float* __restrict__ enorm,
    u16* __restrict__ qb, float* __restrict__ counts, float* __restrict__ pvq) {
  __shared__ float zs[8][DIM];
  __shared__ float sd[8][CODES];
  __shared__ float lred[4];
  int r0 = blockIdx.x * 8;
  for (int q = threadIdx.x; q < 8 * DIM; q += 256) {
    int i = q >> 7, c = q & 127;
    int r = r0 + i; int n = r / HWL, p = r % HWL;
    zs[i][c] = z[(size_t)(n * C + c) * HWL + p];
  }
  __syncthreads();
  float acc[4][8];
#pragma unroll
  for (int k = 0; k < 4; ++k)
#pragma unroll
    for (int i = 0; i < 8; ++i) acc[k][i] = 0.f;
  int t = threadIdx.x;
  for (int c4 = 0; c4 < 32; ++c4) {
    const float4* ep = embp + (size_t)c4 * 1024;
    float4 e0 = ep[t], e1 = ep[t + 256], e2 = ep[t + 512], e3 = ep[t + 768];
#pragma unroll
    for (int i = 0; i < 8; ++i) {
      float4 zv = *(const float4*)(&zs[i][c4 * 4]);
      acc[0][i] = fmaf(zv.x, e0.x, fmaf(zv.y, e0.y, fmaf(zv.z, e0.z, fmaf(zv.w, e0.w, acc[0][i]))));
      acc[1][i] = fmaf(zv.x, e1.x, fmaf(zv.y, e1.y, fmaf(zv.z, e1.z, fmaf(zv.w, e1.w, acc[1][i]))));
      acc[2][i] = fmaf(zv.x, e2.x, fmaf(zv.y, e2.y, fmaf(zv.z, e2.z, fmaf(zv.w, e2.w, acc[2][i]))));
      acc[3][i] = fmaf(zv.x, e3.x, fmaf(zv.y, e3.y, fmaf(zv.z, e3.z, fmaf(zv.w, e3.w, acc[3][i]))));
    }
  }
#pragma unroll
  for (int k = 0; k < 4; ++k) {
    int e = t + k * 256;
    float nv = enorm[e];
#pragma unroll
    for (int i = 0; i < 8; ++i) sd[i][e] = fmaf(-2.f, acc[k][i], nv);
  }
  __syncthreads();
  int wv = threadIdx.x >> 6, ln = threadIdx.x & 63;
  float lpw = 0.f;
  for (int i = wv * 2; i < wv * 2 + 2; ++i) {
    int f0 = -1, f1 = -1; int idxs[3];
#pragma unroll
    for (int pass = 0; pass < 3; ++pass) {
      float bvv = 3.4e38f; int bi = CODES;
      for (int k = 0; k < 16; ++k) {
        int e = ln + k * 64;
        float v = sd[i][e];
        bool skip = (e == f0) || (e == f1);
        if (!skip && v < bvv) { bvv = v; bi = e; }
      }
#pragma unroll
      for (int o = 32; o > 0; o >>= 1) {
        float ov = __shfl_down(bvv, o); int oi = __shfl_down(bi, o);
        if (ov < bvv || (ov == bvv && oi < bi)) { bvv = ov; bi = oi; }
      }
      bi = __shfl(bi, 0);
      idxs[pass] = bi;
      if (pass == 0) f0 = bi; else if (pass == 1) f1 = bi;
    }
    int r = r0 + i;
    const float* q0 = emb + (size_t)idxs[0] * DIM;
    float lp = 0.f;
    for (int c = ln; c < DIM; c += 64) {
      float qv = q0[c];
      qb[(size_t)r * 128 + c] = f2bf(qv);
      float d = zs[i][c] - qv;
      lp = fmaf(d, d, lp);
    }
#pragma unroll
    for (int o = 32; o > 0; o >>= 1) lp += __shfl_down(lp, o);
    if (ln == 0) { lpw += lp; atomicAdd(&counts[idxs[2]], 1.f); }
  }
  if (ln == 0) lred[wv] = lpw;
  __syncthreads();
  if (threadIdx.x == 0) pvq[blockIdx.x] = lred[0] + lred[1] + lred[2] + lred[3];
}

// ---------------- finalize ----------------
__global__ __launch_bounds__(256) void k_finalize(
    const float* __restrict__ counts, const float* __restrict__ pvq, float* __restrict__ out) {
  float local = 0.f;
#pragma unroll
  for (int k = 0; k < 4; ++k) {
    float cnt = counts[threadIdx.x + k * 256];
    float pr = cnt * (1.f / (float)ROWS);
    local = fmaf(pr, logf(pr + 1e-10f), local);
  }
  float lsum = 0.f;
  for (int i = threadIdx.x; i < ROWS / 8; i += 256) lsum += pvq[i];
  if (block_red2(local, lsum)) {
    out[1 + NB * 4 * HW] = expf(-local);
    out[0] = 0.25f * lsum * (1.f / (9216.f * 128.f));
  }
}

// ---------------- proj (1x1) MFMA, fused e0-GN on staged enc1 ----------------
__global__ __launch_bounds__(256) void k_proj_m(
    const float* __restrict__ enc1, const u16* __restrict__ Apj,
    const float* __restrict__ bias, const float* __restrict__ stats0,
    const float* __restrict__ gam, const float* __restrict__ bet,
    u16* __restrict__ skipb) {
  __shared__ u16 Ash[128 * 32];
  __shared__ u16 Bsh[96 * 32];
  int b = blockIdx.x; int rowi = b % 96; int n = b / 96; int px0 = rowi * 96;
  int t = threadIdx.x; int w = t >> 6; int lane = t & 63;
  int ln16 = lane & 15, quad = lane >> 4;
  int co0w = (w & 1) * 64; int pxh = (w >> 1) * 48;
  int c_l = t & 31, xg = t >> 5;
  const float invc = 1.f / (64.f * 9216.f);
  f4v acc[4][3];
#pragma unroll
  for (int mt = 0; mt < 4; ++mt)
#pragma unroll
    for (int nt = 0; nt < 3; ++nt) acc[mt][nt] = (f4v){0.f, 0.f, 0.f, 0.f};
  for (int ch = 0; ch < 4; ++ch) {
    __syncthreads();
#pragma unroll
    for (int e = 0; e < 2; ++e) {
      int i = t + e * 256;
      *(bf8v*)&Ash[i * 8] = *(const bf8v*)&Apj[ch * 4096 + i * 8];
    }
    int c = ch * 32 + c_l;
    const float* st = stats0 + (n * 2 + (ch >> 1)) * 2;
    float mu = st[0] * invc;
    float var = fmaf(-mu, mu, st[1] * invc);
    float rsv = rsqrtf(var + 1e-5f);
    float ga = gam[c], be = bet[c];
    const float* ip = enc1 + (size_t)(n * 128 + c) * 9216 + px0 + xg * 12;
#pragma unroll
    for (int j4 = 0; j4 < 3; ++j4) {
      float4 v = *(const float4*)(ip + j4 * 4);
      int pxb = xg * 12 + j4 * 4;
      Bsh[(pxb + 0) * 32 + c_l] = f2bf(lrelu_f(fmaf((v.x - mu) * rsv, ga, be)));
      Bsh[(pxb + 1) * 32 + c_l] = f2bf(lrelu_f(fmaf((v.y - mu) * rsv, ga, be)));
      Bsh[(pxb + 2) * 32 + c_l] = f2bf(lrelu_f(fmaf((v.z - mu) * rsv, ga, be)));
      Bsh[(pxb + 3) * 32 + c_l] = f2bf(lrelu_f(fmaf((v.w - mu) * rsv, ga, be)));
    }
    __syncthreads();
    bf8v af[4];
#pragma unroll
    for (int mt = 0; mt < 4; ++mt)
      af[mt] = *(const bf8v*)&Ash[(co0w + mt * 16 + ln16) * 32 + quad * 8];
#pragma unroll
    for (int nt = 0; nt < 3; ++nt) {
      bf8v bfv = *(const bf8v*)&Bsh[(pxh + nt * 16 + ln16) * 32 + quad * 8];
#pragma unroll
      for (int mt = 0; mt < 4; ++mt)
        acc[mt][nt] = __builtin_amdgcn_mfma_f32_16x16x32_bf16(af[mt], bfv, acc[mt][nt], 0, 0, 0);
    }
  }
#pragma unroll
  for (int mt = 0; mt < 4; ++mt) {
    int co = co0w + mt * 16 + quad * 4;
    float4 bv = *(const float4*)&bias[co];
#pragma unroll
    for (int nt = 0; nt < 3; ++nt) {
      int px = px0 + pxh + nt * 16 + ln16;
      u16* dp = skipb + (size_t)(n * 9216 + px) * 128 + co;
      s4v sv;
      sv.x = (short)f2bf(acc[mt][nt].x + bv.x);
      sv.y = (short)f2bf(acc[mt][nt].y + bv.y);
      sv.z = (short)f2bf(acc[mt][nt].z + bv.z);
      sv.w = (short)f2bf(acc[mt][nt].w + bv.w);
      *(s4v*)dp = sv;
    }
  }
}

// ---------------- d0 conv-transpose MFMA ----------------
__global__ __launch_bounds__(256) void k_convt_d0m(
    const u16* __restrict__ qb, const u16* __restrict__ A0,
    const float* __restrict__ bias, float* __restrict__ h, float2* __restrict__ ps) {
  __shared__ u16 Ash[2 * 128 * 32];
  __shared__ u16 Bsh[49 * 32];
  int b = blockIdx.x; int rx = b & 1; int oy = (b >> 1) % 96; int n = b / 192;
  int t = threadIdx.x; int w = t >> 6; int lane = t & 63;
  int ln16 = lane & 15, quad = lane >> 4;
  int co0w = w * 32;
  f4v acc[2][3];
#pragma unroll
  for (int mt = 0; mt < 2; ++mt)
#pragma unroll
    for (int nt = 0; nt < 3; ++nt) acc[mt][nt] = (f4v){0.f, 0.f, 0.f, 0.f};
  int nyt, wys[2], iys[2];
  if (oy & 1) {
    wys[0] = 2; iys[0] = (oy - 1) >> 1;
    wys[1] = 0; iys[1] = (oy + 1) >> 1;
    nyt = (iys[1] < 48) ? 2 : 1;
  } else { wys[0] = 1; iys[0] = oy >> 1; wys[1] = 0; iys[1] = 0; nyt = 1; }
  int nxt = rx ? 2 : 1;
  int wxs[2], xof[2];
  if (rx) { wxs[0] = 2; xof[0] = 0; wxs[1] = 0; xof[1] = 1; }
  else { wxs[0] = 1; xof[0] = 0; wxs[1] = 0; xof[1] = 0; }
  for (int yt = 0; yt < nyt; ++yt) {
    for (int ch = 0; ch < 4; ++ch) {
      __syncthreads();
      for (int e = t; e < nxt * 512; e += 256) {
        int xt = e >> 9, e2 = e & 511;
        const u16* Asrc = A0 + (size_t)(((wys[yt] * 4 + ch) * 3 + wxs[xt]) * 4096);
        *(bf8v*)&Ash[xt * 4096 + e2 * 8] = *(const bf8v*)&Asrc[e2 * 8];
      }
      const u16* bbase = qb + (size_t)(n * 2304 + iys[yt] * 48) * 128 + ch * 32;
      for (int e = t; e < 196; e += 256) {
        int row = e >> 2, seg = e & 3;
        bf8v v = {0, 0, 0, 0, 0, 0, 0, 0};
        if (row < 48) v = *(const bf8v*)&bbase[row * 128 + seg * 8];
        *(bf8v*)&Bsh[row * 32 + seg * 8] = v;
      }
      __syncthreads();
      for (int xt = 0; xt < nxt; ++xt) {
        bf8v af[2];
#pragma unroll
        for (int mt = 0; mt < 2; ++mt)
          af[mt] = *(const bf8v*)&Ash[xt * 4096 + (co0w + mt * 16 + ln16) * 32 + quad * 8];
#pragma unroll
        for (int nt = 0; nt < 3; ++nt) {
          bf8v bfv = *(const bf8v*)&Bsh[(nt * 16 + ln16 + xof[xt]) * 32 + quad * 8];
#pragma unroll
          for (int mt = 0; mt < 2; ++mt)
            acc[mt][nt] = __builtin_amdgcn_mfma_f32_16x16x32_bf16(af[mt], bfv, acc[mt][nt], 0, 0, 0);
        }
      }
    }
  }
  float s = 0.f, s2 = 0.f;
#pragma unroll
  for (int mt = 0; mt < 2; ++mt) {
    int co = co0w + mt * 16 + quad * 4;
    float4 bv = *(const float4*)&bias[co];
#pragma unroll
    for (int nt = 0; nt < 3; ++nt) {
      int px = nt * 16 + ln16;
      int ox = 2 * px + rx;
      float4 v;
      v.x = acc[mt][nt].x + bv.x; v.y = acc[mt][nt].y + bv.y;
      v.z = acc[mt][nt].z + bv.z; v.w = acc[mt][nt].w + bv.w;
      *(float4*)(h + (size_t)(n * 9216 + oy * 96 + ox) * 128 + co) = v;
      s += v.x + v.y + v.z + v.w;
      s2 += v.x * v.x + v.y * v.y + v.z * v.z + v.w * v.w;
    }
  }
  wave_red2(s, s2);
  if (lane == 0) {
    int slot = n * 2 + (w >> 1);
    ps[(size_t)slot * 384 + (oy * 2 + rx) * 2 + (w & 1)] = make_float2(s, s2);
  }
}

// ---------------- d1 conv MFMA ----------------
__global__ __launch_bounds__(256) void k_conv_d1m(
    const u16* __restrict__ hb, const u16* __restrict__ sb,
    const u16* __restrict__ A1, const float* __restrict__ bias,
    float* __restrict__ y, float2* __restrict__ ps) {
  __shared__ u16 Ash[3 * 128 * 32];
  __shared__ u16 Bsh[98 * 32];
  int b = blockIdx.x; int oy = b % 96; int n = b / 96;
  int t = threadIdx.x; int w = t >> 6; int lane = t & 63;
  int ln16 = lane & 15, quad = lane >> 4;
  int co0w = (w & 1) * 64; int pxh = (w >> 1) * 48;
  f4v acc[4][3];
#pragma unroll
  for (int mt = 0; mt < 4; ++mt)
#pragma unroll
    for (int nt = 0; nt < 3; ++nt) acc[mt][nt] = (f4v){0.f, 0.f, 0.f, 0.f};
  int ky0 = (oy == 0) ? 1 : 0, ky1 = (oy == 95) ? 1 : 2;
  for (int ky = ky0; ky <= ky1; ++ky) {
    int iy = oy + ky - 1;
    for (int ch = 0; ch < 8; ++ch) {
      const u16* src = (ch < 4) ? hb : sb;
      int c0 = (ch & 3) * 32;
      const u16* Asrc = A1 + (size_t)(ky * 8 + ch) * 12288;
      const u16* bbase = src + (size_t)(n * 9216 + iy * 96) * 128 + c0;
      __syncthreads();
#pragma unroll
      for (int e = 0; e < 6; ++e) {
        int i = t + e * 256;
        *(bf8v*)&Ash[i * 8] = *(const bf8v*)&Asrc[i * 8];
      }
      for (int e = t; e < 392; e += 256) {
        int row = e >> 2, seg = e & 3;
        int ix = row - 1;
        bf8v v = {0, 0, 0, 0, 0, 0, 0, 0};
        if ((unsigned)ix < 96u) v = *(const bf8v*)&bbase[ix * 128 + seg * 8];
        *(bf8v*)&Bsh[row * 32 + seg * 8] = v;
      }
      __syncthreads();
#pragma unroll
      for (int kx = 0; kx < 3; ++kx) {
        bf8v af[4];
#pragma unroll
        for (int mt = 0; mt < 4; ++mt)
          af[mt] = *(const bf8v*)&Ash[(kx * 128 + co0w + mt * 16 + ln16) * 32 + quad * 8];
#pragma unroll
        for (int nt = 0; nt < 3; ++nt) {
          bf8v bfv = *(const bf8v*)&Bsh[(pxh + nt * 16 + ln16 + kx) * 32 + quad * 8];
#pragma unroll
          for (int mt = 0; mt < 4; ++mt)
            acc[mt][nt] = __builtin_amdgcn_mfma_f32_16x16x32_bf16(af[mt], bfv, acc[mt][nt], 0, 0, 0);
        }
      }
    }
  }
  float s = 0.f, s2 = 0.f;
#pragma unroll
  for (int mt = 0; mt < 4; ++mt) {
    int co = co0w + mt * 16 + quad * 4;
    float4 bv = *(const float4*)&bias[co];
#pragma unroll
    for (int nt = 0; nt < 3; ++nt) {
      int px = pxh + nt * 16 + ln16;
      float4 v;
      v.x = acc[mt][nt].x + bv.x; v.y = acc[mt][nt].y + bv.y;
      v.z = acc[mt][nt].z + bv.z; v.w = acc[mt][nt].w + bv.w;
      *(float4*)(y + (size_t)(n * 9216 + oy * 96 + px) * 128 + co) = v;
      s += v.x + v.y + v.z + v.w;
      s2 += v.x * v.x + v.y * v.y + v.z * v.z + v.w * v.w;
    }
  }
  wave_red2(s, s2);
  if (lane == 0) {
    int slot = n * 2 + (w & 1);
    ps[(size_t)slot * 192 + oy * 2 + (w >> 1)] = make_float2(s, s2);
  }
}

// ---------------- readout, fused d1-GN: out(NCHW) = ro_w x GN(y NHWC fp32) ----------------
__global__ __launch_bounds__(256) void k_ro(
    const float* __restrict__ y, const float* __restrict__ w,
    const float* __restrict__ bias, const float* __restrict__ stats3,
    const float* __restrict__ gam, const float* __restrict__ bet,
    float* __restrict__ out) {
  __shared__ float wsh[512];
  __shared__ float gsh[128], bsh[128];
  __shared__ float red[64][16];
  int b = blockIdx.x; int n = b / 144; int px0 = (b % 144) * 64;
  int t = threadIdx.x; int q = t & 3, pxl = t >> 2;
  for (int e = t; e < 512; e += 256) wsh[e] = w[e];
  if (t < 128) { gsh[t] = gam[t]; bsh[t] = bet[t]; }
  __syncthreads();
  const float invc = 1.f / (64.f * 9216.f);
  int g = q >> 1;
  const float* st = stats3 + (n * 2 + g) * 2;
  float mu = st[0] * invc;
  float var = fmaf(-mu, mu, st[1] * invc);
  float rsv = rsqrtf(var + 1e-5f);
  const float* yb = y + (size_t)(n * 9216 + px0 + pxl) * 128 + q * 32;
  float s0 = 0.f, s1 = 0.f, s2 = 0.f, s3 = 0.f;
#pragma unroll
  for (int j = 0; j < 8; ++j) {
    float4 v = *(const float4*)(yb + j * 4);
    int c0 = q * 32 + j * 4;
    float vx = lrelu_f(fmaf((v.x - mu) * rsv, gsh[c0 + 0], bsh[c0 + 0]));
    float vy = lrelu_f(fmaf((v.y - mu) * rsv, gsh[c0 + 1], bsh[c0 + 1]));
    float vz = lrelu_f(fmaf((v.z - mu) * rsv, gsh[c0 + 2], bsh[c0 + 2]));
    float vw = lrelu_f(fmaf((v.w - mu) * rsv, gsh[c0 + 3], bsh[c0 + 3]));
    const float* w0 = &wsh[0 * 128 + c0];
    const float* w1 = &wsh[1 * 128 + c0];
    const float* w2 = &wsh[2 * 128 + c0];
    const float* w3 = &wsh[3 * 128 + c0];
    s0 += vx * w0[0] + vy * w0[1] + vz * w0[2] + vw * w0[3];
    s1 += vx * w1[0] + vy * w1[1] + vz * w1[2] + vw * w1[3];
    s2 += vx * w2[0] + vy * w2[1] + vz * w2[2] + vw * w2[3];
    s3 += vx * w3[0] + vy * w3[1] + vz * w3[2] + vw * w3[3];
  }
  red[pxl][q * 4 + 0] = s0; red[pxl][q * 4 + 1] = s1;
  red[pxl][q * 4 + 2] = s2; red[pxl][q * 4 + 3] = s3;
  __syncthreads();
  float val = red[pxl][0 * 4 + q] + red[pxl][1 * 4 + q] + red[pxl][2 * 4 + q] + red[pxl][3 * 4 + q] + bias[q];
  out[1 + (size_t)(n * 4 + q) * 9216 + px0 + pxl] = val;
}

extern "C" void kernel_launch(void* const* d_in, const int* in_sizes, int n_in,
                              void* d_out, int out_size, void* d_ws, size_t ws_size,
                              hipStream_t stream) {
  (void)in_sizes; (void)n_in; (void)out_size; (void)ws_size;
  const float* x     = (const float*)d_in[0];
  const float* e0_w  = (const float*)d_in[1];
  const float* e0_b  = (const float*)d_in[2];
  const float* e0_g  = (const float*)d_in[3];
  const float* e0_bt = (const float*)d_in[4];
  const float* e1_w  = (const float*)d_in[5];
  const float* e1_b  = (const float*)d_in[6];
  const float* e1_g  = (const float*)d_in[7];
  const float* e1_bt = (const float*)d_in[8];
  const float* pv_w  = (const float*)d_in[9];
  const float* pv_b  = (const float*)d_in[10];
  const float* emb   = (const float*)d_in[11];
  const float* d0_w  = (const float*)d_in[12];
  const float* d0_b  = (const float*)d_in[13];
  const float* d0_g  = (const float*)d_in[14];
  const float* d0_bt = (const float*)d_in[15];
  const float* d1_w  = (const float*)d_in[16];
  const float* d1_b  = (const float*)d_in[17];
  const float* d1_g  = (const float*)d_in[18];
  const float* d1_bt = (const float*)d_in[19];
  const float* pj_w  = (const float*)d_in[20];
  const float* pj_b  = (const float*)d_in[21];
  const float* ro_w  = (const float*)d_in[22];
  const float* ro_b  = (const float*)d_in[23];
  float* out = (float*)d_out;
  float* ws = (float*)d_ws;

  float* stats  = ws;                       // 64
  float* counts = ws + 64;                  // 1024
  float* enorm  = ws + 1088;                // 1024
  float* pvq    = ws + 2112;                // 1152
  float2* ps_e0 = (float2*)(ws + 3264);
  float2* ps_e1 = (float2*)(ws + 76992);
  float2* ps_d0 = (float2*)(ws + 95424);
  float2* ps_d1 = (float2*)(ws + 107712);
  float* enc1   = ws + 114688;                     // 4718592 fp32 NCHW (raw e0 out)
  float* latent = enc1 + (size_t)NB * C * HW;      // 1179648 fp32 NCHW (raw e1 out)
  float* zbuf   = latent + (size_t)NB * C * HWL;   // 1179648 fp32 NCHW
  float* hy     = zbuf + (size_t)NB * C * HWL;     // 4718592 fp32 (e1 4-slice partials; then h,y NHWC)
  u16* qb    = (u16*)(hy + (size_t)NB * C * HW);   // 1179648 bf16 NHWC
  u16* hb    = qb + (size_t)NB * C * HWL;          // 4718592 bf16 NHWC
  u16* skipb = hb + (size_t)NB * C * HW;           // 4718592 bf16 NHWC
  u16* A1    = skipb + (size_t)NB * C * HW;        // 294912
  u16* A0    = A1 + 294912;                        // 147456
  u16* Apj   = A0 + 147456;                        // 16384
  float4* embp = (float4*)(Apj + 16384 + 64);      // 32768 float4
  // gnpad (20.07 MB) aliases qb+hb+skipb (21.2 MB); liveness: gn_pad -> e1s,
  // then k_vq/proj_m/gn_nhwc_bf overwrite. Keeps ws at the proven ~70 MB.
  float* gnpad = (float*)qb;

  hipMemsetAsync(counts, 0, 1024 * sizeof(float), stream);

  k_pack_all<<<1924, 256, 0, stream>>>(d1_w, d0_w, pj_w, emb, A1, A0, Apj, embp, enorm);

  k_conv_e0t<<<3072, 256, 0, stream>>>(x, e0_w, e0_b, enc1, ps_e0);
  k_red16<<<8, 256, 0, stream>>>(ps_e0, stats + 0, 384);
  k_gn_pad<<<512 * 9800 / 256, 256, 0, stream>>>(enc1, stats + 0, e0_g, e0_bt, gnpad);
  k_conv_e1s<<<768, 256, 0, stream>>>(gnpad, e1_w, hy);
  k_e1comb<<<NB * C * HWL / 256, 256, 0, stream>>>(hy, e1_b, latent, ps_e1);
  k_red16<<<8, 256, 0, stream>>>(ps_e1, stats + 16, 576);
  k_pv<<<NB * 2 * 9, 256, 0, stream>>>(latent, pv_w, pv_b, stats + 16, e1_g, e1_bt, zbuf);
  k_vq<<<ROWS / 8, 256, 0, stream>>>(zbuf, embp, emb, enorm, qb, counts, pvq);
  k_finalize<<<1, 256, 0, stream>>>(counts, pvq, out);

  k_proj_m<<<NB * 96, 256, 0, stream>>>(enc1, Apj, pj_b, stats + 0, e0_g, e0_bt, skipb);
  k_convt_d0m<<<NB * 96 * 2, 256, 0, stream>>>(qb, A0, d0_b, hy, ps_d0);
  k_red16<<<8, 256, 0, stream>>>(ps_d0, stats + 32, 384);
  k_gn_nhwc_bf<<<NB * C * HW / 256, 256, 0, stream>>>(hy, hb, stats + 32, d0_g, d0_bt);
  k_conv_d1m<<<NB * 96, 256, 0, stream>>>(hb, skipb, A1, d1_b, hy, ps_d1);
  k_red16<<<8, 256, 0, stream>>>(ps_d1, stats + 48, 192);
  k_ro<<<NB * 144, 256, 0, stream>>>(hy, ro_w, ro_b, stats + 48, d1_g, d1_bt, out);
}

// Round 15
// 391.043 us; speedup vs baseline: 1.0531x; 1.0098x over previous
//
#include <hip/hip_runtime.h>

#define DEVI __device__ __forceinline__

typedef unsigned short u16;
typedef __attribute__((ext_vector_type(8))) short bf8v;   // 8 bf16 = 4 VGPR
typedef __attribute__((ext_vector_type(4))) short s4v;    // 4 bf16
typedef __attribute__((ext_vector_type(4))) float f4v;    // MFMA acc

constexpr int NB = 4, C = 128, H = 96, W = 96, HW = H * W;   // 9216
constexpr int HL = 48, WL = 48, HWL = HL * WL;               // 2304
constexpr int CODES = 1024, DIM = 128;
constexpr int ROWS = NB * HWL;                               // 9216 VQ rows

DEVI float lrelu_f(float v) { return v >= 0.f ? v : 0.2f * v; }

DEVI u16 f2bf(float f) {  // RNE float->bf16
  union { float f; unsigned u; } v; v.f = f;
  unsigned r = (v.u + 0x7FFFu + ((v.u >> 16) & 1u)) >> 16;
  return (u16)r;
}

DEVI void wave_red2(float& s, float& s2) {
#pragma unroll
  for (int o = 32; o > 0; o >>= 1) { s += __shfl_down(s, o); s2 += __shfl_down(s2, o); }
}

DEVI bool block_red2(float& s, float& s2) {
  wave_red2(s, s2);
  __shared__ float ls[8], ls2[8];
  int wv = threadIdx.x >> 6, ln = threadIdx.x & 63;
  if (ln == 0) { ls[wv] = s; ls2[wv] = s2; }
  __syncthreads();
  if (threadIdx.x == 0) {
    s = ls[0] + ls[1] + ls[2] + ls[3];
    s2 = ls2[0] + ls2[1] + ls2[2] + ls2[3];
    return true;
  }
  return false;
}

// ---------------- stats reduction: 8 slots, PER partials each ----------------
__global__ __launch_bounds__(256) void k_red16(const float2* __restrict__ src,
                                               float* __restrict__ dst, int per) {
  int slot = blockIdx.x;
  float s = 0.f, s2 = 0.f;
  for (int i = threadIdx.x; i < per; i += 256) {
    float2 v = src[(size_t)slot * per + i];
    s += v.x; s2 += v.y;
  }
  if (block_red2(s, s2)) { dst[slot * 2] = s; dst[slot * 2 + 1] = s2; }
}

// ---------------- unified pre-pack: d1w | d0w | pjw | emb | embnorm | counts-zero ----------------
__global__ __launch_bounds__(256) void k_pack_all(
    const float* __restrict__ d1_w, const float* __restrict__ d0_w,
    const float* __restrict__ pj_w, const float* __restrict__ emb,
    u16* __restrict__ A1, u16* __restrict__ A0, u16* __restrict__ Apj,
    float4* __restrict__ embp, float* __restrict__ enorm, float* __restrict__ counts) {
  int b = blockIdx.x, t = threadIdx.x;
  if (b < 1152) {                                  // d1: A1[ky][ch8][kx][co128][ci32]
    int i = b * 256 + t;
    int ci = i & 31, co = (i >> 5) & 127, r = i >> 12;
    int kx = r % 3; int r2 = r / 3; int ch = r2 & 7, ky = r2 >> 3;
    A1[i] = f2bf(d1_w[((size_t)(co * 256 + ch * 32 + ci) * 3 + ky) * 3 + kx]);
  } else if (b < 1728) {                           // d0: A0[wy][ch4][wx][co128][ci32]
    int i = (b - 1152) * 256 + t;
    int ci = i & 31, co = (i >> 5) & 127, r = i >> 12;
    int wx = r % 3; int r2 = r / 3; int ch = r2 & 3, wy = r2 >> 2;
    A0[i] = f2bf(d0_w[((size_t)((ch * 32 + ci) * 128 + co) * 3 + wy) * 3 + wx]);
  } else if (b < 1792) {                           // pj: Apj[ch4][co128][ci32]
    int i = (b - 1728) * 256 + t;
    int ci = i & 31, co = (i >> 5) & 127, ch = i >> 12;
    Apj[i] = f2bf(pj_w[co * 128 + ch * 32 + ci]);
  } else if (b < 1920) {                           // emb pack: embp[k4][code]
    int i = (b - 1792) * 256 + t;
    int k4 = i & 31, code = i >> 5;
    embp[(size_t)k4 * 1024 + code] = *(const float4*)&emb[(size_t)code * DIM + k4 * 4];
  } else if (b < 1924) {                           // emb row norms (4 blocks)
    int e = (b - 1920) * 256 + t;
    const float4* p = (const float4*)(emb + (size_t)e * DIM);
    float s = 0.f;
#pragma unroll 8
    for (int i = 0; i < 32; ++i) {
      float4 v = p[i];
      s = fmaf(v.x, v.x, s); s = fmaf(v.y, v.y, s); s = fmaf(v.z, v.z, s); s = fmaf(v.w, v.w, s);
    }
    enorm[e] = s;
  } else {                                         // zero counts (1 block)
#pragma unroll
    for (int k = 0; k < 4; ++k) counts[t + k * 256] = 0.f;
  }
}

// ---------------- conv e0 tiled: 3x3, Cin=4, s=1, p=1; block = (n,co,16 rows) ----------------
__global__ __launch_bounds__(256) void k_conv_e0t(
    const float* __restrict__ x, const float* __restrict__ wg,
    const float* __restrict__ bias, float* __restrict__ out, float2* __restrict__ ps) {
  __shared__ float xs[4][18][104];
  int b = blockIdx.x;
  int rq = b % 6; int co = (b / 6) & 127; int n = b / 768;
  int t = threadIdx.x;
  int tx = t & 15, r = t >> 4;
  int y0 = rq * 16;
  for (int e = t; e < 4 * 18 * 104; e += 256) {
    int ci = e / 1872; int rem = e - ci * 1872;
    int row = rem / 104; int off = rem - row * 104;
    int iy = y0 - 1 + row; int ix = off - 1;
    float v = 0.f;
    if ((unsigned)iy < 96u && (unsigned)ix < 96u)
      v = x[((size_t)(n * 4 + ci)) * HW + iy * 96 + ix];
    xs[ci][row][off] = v;
  }
  float wr[4][9];
  const float* wp = wg + co * 36;
#pragma unroll
  for (int ci = 0; ci < 4; ++ci)
#pragma unroll
    for (int k = 0; k < 9; ++k) wr[ci][k] = wp[ci * 9 + k];
  float bv = bias[co];
  __syncthreads();
  float acc[6];
#pragma unroll
  for (int p = 0; p < 6; ++p) acc[p] = bv;
#pragma unroll
  for (int ci = 0; ci < 4; ++ci) {
#pragma unroll
    for (int ky = 0; ky < 3; ++ky) {
      const float* rp = &xs[ci][r + ky][6 * tx];
      float f[8];
#pragma unroll
      for (int j = 0; j < 4; ++j) {
        float2 v2 = *(const float2*)(rp + 2 * j);
        f[2 * j] = v2.x; f[2 * j + 1] = v2.y;
      }
      float w0 = wr[ci][ky * 3 + 0], w1 = wr[ci][ky * 3 + 1], w2 = wr[ci][ky * 3 + 2];
#pragma unroll
      for (int p = 0; p < 6; ++p)
        acc[p] = fmaf(w0, f[p], fmaf(w1, f[p + 1], fmaf(w2, f[p + 2], acc[p])));
    }
  }
  float* op = out + ((size_t)(n * 128 + co) * 96 + (y0 + r)) * 96 + 6 * tx;
#pragma unroll
  for (int j = 0; j < 3; ++j) {
    float2 v2 = { acc[2 * j], acc[2 * j + 1] };
    *(float2*)(op + 2 * j) = v2;
  }
  float s = 0.f, s2 = 0.f;
#pragma unroll
  for (int p = 0; p < 6; ++p) { s += acc[p]; s2 += acc[p] * acc[p]; }
  if (block_red2(s, s2)) {
    int slot = n * 2 + (co >> 6);
    ps[(size_t)slot * 384 + (co & 63) * 6 + rq] = make_float2(s, s2);
  }
}

// ---------------- GN(e0)+lrelu into padded fp32 buffer gnpad[n][c][98][100] ----------------
__global__ __launch_bounds__(256) void k_gn_pad(
    const float* __restrict__ in, const float* __restrict__ stats,
    const float* __restrict__ gam, const float* __restrict__ bet, float* __restrict__ outp) {
  int idx = blockIdx.x * 256 + threadIdx.x;        // 512*9800 = 5017600
  int col = idx % 100; int r2 = idx / 100; int row = r2 % 98; int c2 = r2 / 98;
  int c = c2 & 127; int n = c2 >> 7;
  float v = 0.f;
  if (row >= 1 && row <= 96 && col >= 1 && col <= 96) {
    const float* st = stats + (n * 2 + (c >> 6)) * 2;
    const float invc = 1.f / (64.f * 9216.f);
    float mu = st[0] * invc;
    float var = fmaf(-mu, mu, st[1] * invc);
    float rs = rsqrtf(var + 1e-5f);
    float raw = in[(size_t)c2 * 9216 + (row - 1) * 96 + (col - 1)];
    v = lrelu_f(fmaf((raw - mu) * rs, gam[c], bet[c]));
  }
  outp[idx] = v;
}

// ---------------- GN + lrelu, NHWC fp32 -> bf16 (d0 layer) ----------------
__global__ __launch_bounds__(256) void k_gn_nhwc_bf(
    const float* __restrict__ in, u16* __restrict__ outb, const float* __restrict__ stats,
    const float* __restrict__ gam, const float* __restrict__ bet) {
  int idx = blockIdx.x * 256 + threadIdx.x;
  int c = idx & 127;
  int n = idx / (9216 * 128);
  const float* st = stats + (n * 2 + (c >> 6)) * 2;
  const float invcnt = 1.f / (64.f * 9216.f);
  float mu = st[0] * invcnt;
  float var = fmaf(-mu, mu, st[1] * invcnt);
  float rs = rsqrtf(var + 1e-5f);
  float v = in[idx];
  outb[idx] = f2bf(lrelu_f(fmaf((v - mu) * rs, gam[c], bet[c])));
}

// ---------------- e1 split-K(4) fp32 from gnpad: 3x3, Cin=128, stride 2 ----------------
__global__ __launch_bounds__(256, 4) void k_conv_e1s(
    const float* __restrict__ gnpad, const float* __restrict__ wg, float* __restrict__ part) {
  __shared__ float insh[8 * 500];     // [ci8][row5][100 stride] 16 KB
  __shared__ float wsh[8 * 576];      // [ci8][k9][co64] 18.4 KB
  int b = blockIdx.x;
  int cb = b & 1; int kb = (b >> 1) & 3; int rq = (b >> 3) % 24; int n = b / 192;
  int co0 = cb * 64;
  int t = threadIdx.x;
  int tx = t & 15, r = (t >> 4) & 1, cg = t >> 5;
  float acc[8][3];
#pragma unroll
  for (int c = 0; c < 8; ++c)
#pragma unroll
    for (int p = 0; p < 3; ++p) acc[c][p] = 0.f;
  for (int cc = 0; cc < 4; ++cc) {
    __syncthreads();
    const float4* src = (const float4*)(gnpad + ((size_t)(n * 128 + kb * 32 + cc * 8)) * 9800 + 4 * rq * 100);
#pragma unroll
    for (int j = 0; j < 4; ++j) {
      int e = t + j * 256;
      if (e < 1000) {
        int ci = e / 125; int q = e - ci * 125;
        *(float4*)&insh[ci * 500 + q * 4] = src[(size_t)ci * 2450 + q];
      }
    }
#pragma unroll
    for (int j = 0; j < 18; ++j) {
      int e = t + j * 256;
      int ci = e / 576; int rem = e - ci * 576; int k = rem >> 6; int co = rem & 63;
      wsh[e] = wg[(size_t)(co0 + co) * 1152 + (kb * 32 + cc * 8 + ci) * 9 + k];
    }
    __syncthreads();
#pragma unroll
    for (int ci = 0; ci < 8; ++ci) {
      float iv[3][3][3];
      int ib = ci * 500 + (2 * r) * 100 + 2 * tx;
#pragma unroll
      for (int ky = 0; ky < 3; ++ky) {
#pragma unroll
        for (int p = 0; p < 3; ++p) {
          int a = ib + ky * 100 + 32 * p;
          float2 v2 = *(const float2*)&insh[a];
          iv[ky][p][0] = v2.x; iv[ky][p][1] = v2.y; iv[ky][p][2] = insh[a + 2];
        }
      }
#pragma unroll
      for (int k = 0; k < 9; ++k) {
        float4 wa = *(const float4*)&wsh[ci * 576 + k * 64 + cg * 8];
        float4 wb = *(const float4*)&wsh[ci * 576 + k * 64 + cg * 8 + 4];
        int ky = k / 3, kx = k - ky * 3;
#pragma unroll
        for (int p = 0; p < 3; ++p) {
          float ivv = iv[ky][p][kx];
          acc[0][p] = fmaf(wa.x, ivv, acc[0][p]);
          acc[1][p] = fmaf(wa.y, ivv, acc[1][p]);
          acc[2][p] = fmaf(wa.z, ivv, acc[2][p]);
          acc[3][p] = fmaf(wa.w, ivv, acc[3][p]);
          acc[4][p] = fmaf(wb.x, ivv, acc[4][p]);
          acc[5][p] = fmaf(wb.y, ivv, acc[5][p]);
          acc[6][p] = fmaf(wb.z, ivv, acc[6][p]);
          acc[7][p] = fmaf(wb.w, ivv, acc[7][p]);
        }
      }
    }
  }
  int oy = 2 * rq + r;
#pragma unroll
  for (int c = 0; c < 8; ++c) {
    size_t ob = (size_t)kb * 1179648 + ((size_t)(n * 128 + co0 + cg * 8 + c)) * HWL + oy * 48 + tx;
#pragma unroll
    for (int p = 0; p < 3; ++p) part[ob + 16 * p] = acc[c][p];
  }
}

// ---------------- e1 combine ----------------
__global__ __launch_bounds__(256) void k_e1comb(
    const float* __restrict__ part, const float* __restrict__ bias,
    float* __restrict__ latent, float2* __restrict__ ps) {
  int idx = blockIdx.x * 256 + threadIdx.x;
  int c = (idx / HWL) & 127;
  int n = idx / (HWL * 128);
  float v = part[idx] + part[idx + 1179648] + part[idx + 2 * 1179648] + part[idx + 3 * 1179648] + bias[c];
  latent[idx] = v;
  float s = v, s2 = v * v;
  if (block_red2(s, s2)) {
    int slot = n * 2 + (c >> 6);
    int j = blockIdx.x % 9;
    ps[(size_t)slot * 576 + (c & 63) * 9 + j] = make_float2(s, s2);
  }
}

// ---------------- pv 1x1 conv fp32, fused e1-GN: 64px x 64co per block ----------------
// grid: pxb(36) x cb(2) x n(4) = 288 blocks; thread: pxg(8)x8px, cg(32)x2co
__global__ __launch_bounds__(256, 2) void k_pv(
    const float* __restrict__ in, const float* __restrict__ w,
    const float* __restrict__ bias, const float* __restrict__ stats1,
    const float* __restrict__ gam, const float* __restrict__ bet,
    float* __restrict__ out) {
  int b = blockIdx.x;
  int pxb = b % 36; int cb = (b / 36) & 1; int n = b / 72;
  int t = threadIdx.x;
  int pxg = t & 7, cg = t >> 3;
  int px0 = pxb * 64 + pxg * 8;
  int cobase = cb * 64 + cg * 2;
  const float invc = 1.f / (64.f * 2304.f);
  float acc[2][8];
#pragma unroll
  for (int c = 0; c < 2; ++c) {
    float bv = bias[cobase + c];
#pragma unroll
    for (int p = 0; p < 8; ++p) acc[c][p] = bv;
  }
  const float* ipb = in + (size_t)n * 128 * HWL + px0;
  for (int ci0 = 0; ci0 < 128; ci0 += 4) {
    float inr[4][8];
#pragma unroll
    for (int i = 0; i < 4; ++i) {
      int c = ci0 + i;
      const float* st = stats1 + (n * 2 + (c >> 6)) * 2;
      float mu = st[0] * invc;
      float var = fmaf(-mu, mu, st[1] * invc);
      float rsv = rsqrtf(var + 1e-5f);
      float ga = gam[c], be = bet[c];
      const float* ip = ipb + (size_t)c * HWL;
      float4 a = *(const float4*)ip; float4 bq = *(const float4*)(ip + 4);
      inr[i][0] = lrelu_f(fmaf((a.x - mu) * rsv, ga, be));
      inr[i][1] = lrelu_f(fmaf((a.y - mu) * rsv, ga, be));
      inr[i][2] = lrelu_f(fmaf((a.z - mu) * rsv, ga, be));
      inr[i][3] = lrelu_f(fmaf((a.w - mu) * rsv, ga, be));
      inr[i][4] = lrelu_f(fmaf((bq.x - mu) * rsv, ga, be));
      inr[i][5] = lrelu_f(fmaf((bq.y - mu) * rsv, ga, be));
      inr[i][6] = lrelu_f(fmaf((bq.z - mu) * rsv, ga, be));
      inr[i][7] = lrelu_f(fmaf((bq.w - mu) * rsv, ga, be));
    }
    float wr[2][4];
#pragma unroll
    for (int c = 0; c < 2; ++c) {
      float4 wv = *(const float4*)&w[(size_t)(cobase + c) * 128 + ci0];
      wr[c][0] = wv.x; wr[c][1] = wv.y; wr[c][2] = wv.z; wr[c][3] = wv.w;
    }
#pragma unroll
    for (int i = 0; i < 4; ++i)
#pragma unroll
      for (int c = 0; c < 2; ++c)
#pragma unroll
        for (int p = 0; p < 8; ++p) acc[c][p] = fmaf(wr[c][i], inr[i][p], acc[c][p]);
  }
#pragma unroll
  for (int c = 0; c < 2; ++c) {
    float* op = out + (size_t)(n * 128 + cobase + c) * HWL + px0;
    float4 v0 = { acc[c][0], acc[c][1], acc[c][2], acc[c][3] };
    float4 v1 = { acc[c][4], acc[c][5], acc[c][6], acc[c][7] };
    *(float4*)op = v0; *(float4*)(op + 4) = v1;
  }
}

// ---------------- VQ: fp32 distances (coalesced embp) + top-3 (R11 version) ----------------
__global__ __launch_bounds__(256) void k_vq(
    const float* __restrict__ z, const float4* __restrict__ embp,
    const float* __restrict__ emb, const float* __restrict__ enorm,
    u16* __restrict__ qb, float* __restrict__ counts, float* __restrict__ pvq) {
  __shared__ float zs[8][DIM];
  __shared__ float sd[8][CODES];
  __shared__ float lred[4];
  int r0 = blockIdx.x * 8;
  for (int q = threadIdx.x; q < 8 * DIM; q += 256) {
    int i = q >> 7, c = q & 127;
    int r = r0 + i; int n = r / HWL, p = r % HWL;
    zs[i][c] = z[(size_t)(n * C + c) * HWL + p];
  }
  __syncthreads();
  float acc[4][8];
#pragma unroll
  for (int k = 0; k < 4; ++k)
#pragma unroll
    for (int i = 0; i < 8; ++i) acc[k][i] = 0.f;
  int t = threadIdx.x;
  for (int c4 = 0; c4 < 32; ++c4) {
    const float4* ep = embp + (size_t)c4 * 1024;
    float4 e0 = ep[t], e1 = ep[t + 256], e2 = ep[t + 512], e3 = ep[t + 768];
#pragma unroll
    for (int i = 0; i < 8; ++i) {
      float4 zv = *(const float4*)(&zs[i][c4 * 4]);
      acc[0][i] = fmaf(zv.x, e0.x, fmaf(zv.y, e0.y, fmaf(zv.z, e0.z, fmaf(zv.w, e0.w, acc[0][i]))));
      acc[1][i] = fmaf(zv.x, e1.x, fmaf(zv.y, e1.y, fmaf(zv.z, e1.z, fmaf(zv.w, e1.w, acc[1][i]))));
      acc[2][i] = fmaf(zv.x, e2.x, fmaf(zv.y, e2.y, fmaf(zv.z, e2.z, fmaf(zv.w, e2.w, acc[2][i]))));
      acc[3][i] = fmaf(zv.x, e3.x, fmaf(zv.y, e3.y, fmaf(zv.z, e3.z, fmaf(zv.w, e3.w, acc[3][i]))));
    }
  }
#pragma unroll
  for (int k = 0; k < 4; ++k) {
    int e = t + k * 256;
    float nv = enorm[e];
#pragma unroll
    for (int i = 0; i < 8; ++i) sd[i][e] = fmaf(-2.f, acc[k][i], nv);
  }
  __syncthreads();
  int wv = threadIdx.x >> 6, ln = threadIdx.x & 63;
  float lpw = 0.f;
  for (int i = wv * 2; i < wv * 2 + 2; ++i) {
    int f0 = -1, f1 = -1; int idxs[3];
#pragma unroll
    for (int pass = 0; pass < 3; ++pass) {
      float bvv = 3.4e38f; int bi = CODES;
      for (int k = 0; k < 16; ++k) {
        int e = ln + k * 64;
        float v = sd[i][e];
        bool skip = (e == f0) || (e == f1);
        if (!skip && v < bvv) { bvv = v; bi = e; }
      }
#pragma unroll
      for (int o = 32; o > 0; o >>= 1) {
        float ov = __shfl_down(bvv, o); int oi = __shfl_down(bi, o);
        if (ov < bvv || (ov == bvv && oi < bi)) { bvv = ov; bi = oi; }
      }
      bi = __shfl(bi, 0);
      idxs[pass] = bi;
      if (pass == 0) f0 = bi; else if (pass == 1) f1 = bi;
    }
    int r = r0 + i;
    const float* q0 = emb + (size_t)idxs[0] * DIM;
    float lp = 0.f;
    for (int c = ln; c < DIM; c += 64) {
      float qv = q0[c];
      qb[(size_t)r * 128 + c] = f2bf(qv);
      float d = zs[i][c] - qv;
      lp = fmaf(d, d, lp);
    }
#pragma unroll
    for (int o = 32; o > 0; o >>= 1) lp += __shfl_down(lp, o);
    if (ln == 0) { lpw += lp; atomicAdd(&counts[idxs[2]], 1.f); }
  }
  if (ln == 0) lred[wv] = lpw;
  __syncthreads();
  if (threadIdx.x == 0) pvq[blockIdx.x] = lred[0] + lred[1] + lred[2] + lred[3];
}

// ---------------- finalize ----------------
__global__ __launch_bounds__(256) void k_finalize(
    const float* __restrict__ counts, const float* __restrict__ pvq, float* __restrict__ out) {
  float local = 0.f;
#pragma unroll
  for (int k = 0; k < 4; ++k) {
    float cnt = counts[threadIdx.x + k * 256];
    float pr = cnt * (1.f / (float)ROWS);
    local = fmaf(pr, logf(pr + 1e-10f), local);
  }
  float lsum = 0.f;
  for (int i = threadIdx.x; i < ROWS / 8; i += 256) lsum += pvq[i];
  if (block_red2(local, lsum)) {
    out[1 + NB * 4 * HW] = expf(-local);
    out[0] = 0.25f * lsum * (1.f / (9216.f * 128.f));
  }
}

// ---------------- proj (1x1) MFMA, fused e0-GN on staged enc1 ----------------
__global__ __launch_bounds__(256) void k_proj_m(
    const float* __restrict__ enc1, const u16* __restrict__ Apj,
    const float* __restrict__ bias, const float* __restrict__ stats0,
    const float* __restrict__ gam, const float* __restrict__ bet,
    u16* __restrict__ skipb) {
  __shared__ u16 Ash[128 * 32];
  __shared__ u16 Bsh[96 * 32];
  int b = blockIdx.x; int rowi = b % 96; int n = b / 96; int px0 = rowi * 96;
  int t = threadIdx.x; int w = t >> 6; int lane = t & 63;
  int ln16 = lane & 15, quad = lane >> 4;
  int co0w = (w & 1) * 64; int pxh = (w >> 1) * 48;
  int c_l = t & 31, xg = t >> 5;
  const float invc = 1.f / (64.f * 9216.f);
  f4v acc[4][3];
#pragma unroll
  for (int mt = 0; mt < 4; ++mt)
#pragma unroll
    for (int nt = 0; nt < 3; ++nt) acc[mt][nt] = (f4v){0.f, 0.f, 0.f, 0.f};
  for (int ch = 0; ch < 4; ++ch) {
    __syncthreads();
#pragma unroll
    for (int e = 0; e < 2; ++e) {
      int i = t + e * 256;
      *(bf8v*)&Ash[i * 8] = *(const bf8v*)&Apj[ch * 4096 + i * 8];
    }
    int c = ch * 32 + c_l;
    const float* st = stats0 + (n * 2 + (ch >> 1)) * 2;
    float mu = st[0] * invc;
    float var = fmaf(-mu, mu, st[1] * invc);
    float rsv = rsqrtf(var + 1e-5f);
    float ga = gam[c], be = bet[c];
    const float* ip = enc1 + (size_t)(n * 128 + c) * 9216 + px0 + xg * 12;
#pragma unroll
    for (int j4 = 0; j4 < 3; ++j4) {
      float4 v = *(const float4*)(ip + j4 * 4);
      int pxb = xg * 12 + j4 * 4;
      Bsh[(pxb + 0) * 32 + c_l] = f2bf(lrelu_f(fmaf((v.x - mu) * rsv, ga, be)));
      Bsh[(pxb + 1) * 32 + c_l] = f2bf(lrelu_f(fmaf((v.y - mu) * rsv, ga, be)));
      Bsh[(pxb + 2) * 32 + c_l] = f2bf(lrelu_f(fmaf((v.z - mu) * rsv, ga, be)));
      Bsh[(pxb + 3) * 32 + c_l] = f2bf(lrelu_f(fmaf((v.w - mu) * rsv, ga, be)));
    }
    __syncthreads();
    bf8v af[4];
#pragma unroll
    for (int mt = 0; mt < 4; ++mt)
      af[mt] = *(const bf8v*)&Ash[(co0w + mt * 16 + ln16) * 32 + quad * 8];
#pragma unroll
    for (int nt = 0; nt < 3; ++nt) {
      bf8v bfv = *(const bf8v*)&Bsh[(pxh + nt * 16 + ln16) * 32 + quad * 8];
#pragma unroll
      for (int mt = 0; mt < 4; ++mt)
        acc[mt][nt] = __builtin_amdgcn_mfma_f32_16x16x32_bf16(af[mt], bfv, acc[mt][nt], 0, 0, 0);
    }
  }
#pragma unroll
  for (int mt = 0; mt < 4; ++mt) {
    int co = co0w + mt * 16 + quad * 4;
    float4 bv = *(const float4*)&bias[co];
#pragma unroll
    for (int nt = 0; nt < 3; ++nt) {
      int px = px0 + pxh + nt * 16 + ln16;
      u16* dp = skipb + (size_t)(n * 9216 + px) * 128 + co;
      s4v sv;
      sv.x = (short)f2bf(acc[mt][nt].x + bv.x);
      sv.y = (short)f2bf(acc[mt][nt].y + bv.y);
      sv.z = (short)f2bf(acc[mt][nt].z + bv.z);
      sv.w = (short)f2bf(acc[mt][nt].w + bv.w);
      *(s4v*)dp = sv;
    }
  }
}

// ---------------- d0 conv-transpose MFMA ----------------
__global__ __launch_bounds__(256) void k_convt_d0m(
    const u16* __restrict__ qb, const u16* __restrict__ A0,
    const float* __restrict__ bias, float* __restrict__ h, float2* __restrict__ ps) {
  __shared__ u16 Ash[2 * 128 * 32];
  __shared__ u16 Bsh[49 * 32];
  int b = blockIdx.x; int rx = b & 1; int oy = (b >> 1) % 96; int n = b / 192;
  int t = threadIdx.x; int w = t >> 6; int lane = t & 63;
  int ln16 = lane & 15, quad = lane >> 4;
  int co0w = w * 32;
  f4v acc[2][3];
#pragma unroll
  for (int mt = 0; mt < 2; ++mt)
#pragma unroll
    for (int nt = 0; nt < 3; ++nt) acc[mt][nt] = (f4v){0.f, 0.f, 0.f, 0.f};
  int nyt, wys[2], iys[2];
  if (oy & 1) {
    wys[0] = 2; iys[0] = (oy - 1) >> 1;
    wys[1] = 0; iys[1] = (oy + 1) >> 1;
    nyt = (iys[1] < 48) ? 2 : 1;
  } else { wys[0] = 1; iys[0] = oy >> 1; wys[1] = 0; iys[1] = 0; nyt = 1; }
  int nxt = rx ? 2 : 1;
  int wxs[2], xof[2];
  if (rx) { wxs[0] = 2; xof[0] = 0; wxs[1] = 0; xof[1] = 1; }
  else { wxs[0] = 1; xof[0] = 0; wxs[1] = 0; xof[1] = 0; }
  for (int yt = 0; yt < nyt; ++yt) {
    for (int ch = 0; ch < 4; ++ch) {
      __syncthreads();
      for (int e = t; e < nxt * 512; e += 256) {
        int xt = e >> 9, e2 = e & 511;
        const u16* Asrc = A0 + (size_t)(((wys[yt] * 4 + ch) * 3 + wxs[xt]) * 4096);
        *(bf8v*)&Ash[xt * 4096 + e2 * 8] = *(const bf8v*)&Asrc[e2 * 8];
      }
      const u16* bbase = qb + (size_t)(n * 2304 + iys[yt] * 48) * 128 + ch * 32;
      for (int e = t; e < 196; e += 256) {
        int row = e >> 2, seg = e & 3;
        bf8v v = {0, 0, 0, 0, 0, 0, 0, 0};
        if (row < 48) v = *(const bf8v*)&bbase[row * 128 + seg * 8];
        *(bf8v*)&Bsh[row * 32 + seg * 8] = v;
      }
      __syncthreads();
      for (int xt = 0; xt < nxt; ++xt) {
        bf8v af[2];
#pragma unroll
        for (int mt = 0; mt < 2; ++mt)
          af[mt] = *(const bf8v*)&Ash[xt * 4096 + (co0w + mt * 16 + ln16) * 32 + quad * 8];
#pragma unroll
        for (int nt = 0; nt < 3; ++nt) {
          bf8v bfv = *(const bf8v*)&Bsh[(nt * 16 + ln16 + xof[xt]) * 32 + quad * 8];
#pragma unroll
          for (int mt = 0; mt < 2; ++mt)
            acc[mt][nt] = __builtin_amdgcn_mfma_f32_16x16x32_bf16(af[mt], bfv, acc[mt][nt], 0, 0, 0);
        }
      }
    }
  }
  float s = 0.f, s2 = 0.f;
#pragma unroll
  for (int mt = 0; mt < 2; ++mt) {
    int co = co0w + mt * 16 + quad * 4;
    float4 bv = *(const float4*)&bias[co];
#pragma unroll
    for (int nt = 0; nt < 3; ++nt) {
      int px = nt * 16 + ln16;
      int ox = 2 * px + rx;
      float4 v;
      v.x = acc[mt][nt].x + bv.x; v.y = acc[mt][nt].y + bv.y;
      v.z = acc[mt][nt].z + bv.z; v.w = acc[mt][nt].w + bv.w;
      *(float4*)(h + (size_t)(n * 9216 + oy * 96 + ox) * 128 + co) = v;
      s += v.x + v.y + v.z + v.w;
      s2 += v.x * v.x + v.y * v.y + v.z * v.z + v.w * v.w;
    }
  }
  wave_red2(s, s2);
  if (lane == 0) {
    int slot = n * 2 + (w >> 1);
    ps[(size_t)slot * 384 + (oy * 2 + rx) * 2 + (w & 1)] = make_float2(s, s2);
  }
}

// ---------------- d1 conv MFMA: co-split, 64co x 96px per block ----------------
// grid: cb(2) x oy(96) x n(4) = 768; waves: (w&1)=co 32-half, (w>>1)=px half
// partials: slot = n*2 + cb; off = oy*4 + w; PER = 384
__global__ __launch_bounds__(256) void k_conv_d1m(
    const u16* __restrict__ hb, const u16* __restrict__ sb,
    const u16* __restrict__ A1, const float* __restrict__ bias,
    float* __restrict__ y, float2* __restrict__ ps) {
  __shared__ u16 Ash[3 * 64 * 32];   // [kx][co64][ci32] 12 KB
  __shared__ u16 Bsh[98 * 32];       // ~6.1 KB
  int b = blockIdx.x; int cb = b & 1; int oy = (b >> 1) % 96; int n = b / 192;
  int t = threadIdx.x; int w = t >> 6; int lane = t & 63;
  int ln16 = lane & 15, quad = lane >> 4;
  int co0w = (w & 1) * 32; int pxh = (w >> 1) * 48;
  f4v acc[2][3];
#pragma unroll
  for (int mt = 0; mt < 2; ++mt)
#pragma unroll
    for (int nt = 0; nt < 3; ++nt) acc[mt][nt] = (f4v){0.f, 0.f, 0.f, 0.f};
  int ky0 = (oy == 0) ? 1 : 0, ky1 = (oy == 95) ? 1 : 2;
  for (int ky = ky0; ky <= ky1; ++ky) {
    int iy = oy + ky - 1;
    for (int ch = 0; ch < 8; ++ch) {
      const u16* src = (ch < 4) ? hb : sb;
      int c0 = (ch & 3) * 32;
      const u16* Asrc = A1 + (size_t)(ky * 8 + ch) * 12288;
      const u16* bbase = src + (size_t)(n * 9216 + iy * 96) * 128 + c0;
      __syncthreads();
#pragma unroll
      for (int j = 0; j < 3; ++j) {
        int e = t + j * 256;                // e < 768: kx = e>>8, co_l = (e&255)>>2, seg = e&3
        int kx = e >> 8; int e2 = e & 255; int co_l = e2 >> 2; int seg = e2 & 3;
        *(bf8v*)&Ash[(kx * 64 + co_l) * 32 + seg * 8] =
            *(const bf8v*)&Asrc[(size_t)kx * 4096 + (cb * 64 + co_l) * 32 + seg * 8];
      }
      for (int e = t; e < 392; e += 256) {
        int row = e >> 2, seg = e & 3;
        int ix = row - 1;
        bf8v v = {0, 0, 0, 0, 0, 0, 0, 0};
        if ((unsigned)ix < 96u) v = *(const bf8v*)&bbase[ix * 128 + seg * 8];
        *(bf8v*)&Bsh[row * 32 + seg * 8] = v;
      }
      __syncthreads();
#pragma unroll
      for (int kx = 0; kx < 3; ++kx) {
        bf8v af[2];
#pragma unroll
        for (int mt = 0; mt < 2; ++mt)
          af[mt] = *(const bf8v*)&Ash[(kx * 64 + co0w + mt * 16 + ln16) * 32 + quad * 8];
#pragma unroll
        for (int nt = 0; nt < 3; ++nt) {
          bf8v bfv = *(const bf8v*)&Bsh[(pxh + nt * 16 + ln16 + kx) * 32 + quad * 8];
#pragma unroll
          for (int mt = 0; mt < 2; ++mt)
            acc[mt][nt] = __builtin_amdgcn_mfma_f32_16x16x32_bf16(af[mt], bfv, acc[mt][nt], 0, 0, 0);
        }
      }
    }
  }
  float s = 0.f, s2 = 0.f;
#pragma unroll
  for (int mt = 0; mt < 2; ++mt) {
    int co = cb * 64 + co0w + mt * 16 + quad * 4;
    float4 bv = *(const float4*)&bias[co];
#pragma unroll
    for (int nt = 0; nt < 3; ++nt) {
      int px = pxh + nt * 16 + ln16;
      float4 v;
      v.x = acc[mt][nt].x + bv.x; v.y = acc[mt][nt].y + bv.y;
      v.z = acc[mt][nt].z + bv.z; v.w = acc[mt][nt].w + bv.w;
      *(float4*)(y + (size_t)(n * 9216 + oy * 96 + px) * 128 + co) = v;
      s += v.x + v.y + v.z + v.w;
      s2 += v.x * v.x + v.y * v.y + v.z * v.z + v.w * v.w;
    }
  }
  wave_red2(s, s2);
  if (lane == 0) {
    int slot = n * 2 + cb;
    ps[(size_t)slot * 384 + oy * 4 + w] = make_float2(s, s2);
  }
}

// ---------------- readout, fused d1-GN: out(NCHW) = ro_w x GN(y NHWC fp32) ----------------
__global__ __launch_bounds__(256) void k_ro(
    const float* __restrict__ y, const float* __restrict__ w,
    const float* __restrict__ bias, const float* __restrict__ stats3,
    const float* __restrict__ gam, const float* __restrict__ bet,
    float* __restrict__ out) {
  __shared__ float wsh[512];
  __shared__ float gsh[128], bsh[128];
  __shared__ float red[64][16];
  int b = blockIdx.x; int n = b / 144; int px0 = (b % 144) * 64;
  int t = threadIdx.x; int q = t & 3, pxl = t >> 2;
  for (int e = t; e < 512; e += 256) wsh[e] = w[e];
  if (t < 128) { gsh[t] = gam[t]; bsh[t] = bet[t]; }
  __syncthreads();
  const float invc = 1.f / (64.f * 9216.f);
  int g = q >> 1;
  const float* st = stats3 + (n * 2 + g) * 2;
  float mu = st[0] * invc;
  float var = fmaf(-mu, mu, st[1] * invc);
  float rsv = rsqrtf(var + 1e-5f);
  const float* yb = y + (size_t)(n * 9216 + px0 + pxl) * 128 + q * 32;
  float s0 = 0.f, s1 = 0.f, s2 = 0.f, s3 = 0.f;
#pragma unroll
  for (int j = 0; j < 8; ++j) {
    float4 v = *(const float4*)(yb + j * 4);
    int c0 = q * 32 + j * 4;
    float vx = lrelu_f(fmaf((v.x - mu) * rsv, gsh[c0 + 0], bsh[c0 + 0]));
    float vy = lrelu_f(fmaf((v.y - mu) * rsv, gsh[c0 + 1], bsh[c0 + 1]));
    float vz = lrelu_f(fmaf((v.z - mu) * rsv, gsh[c0 + 2], bsh[c0 + 2]));
    float vw = lrelu_f(fmaf((v.w - mu) * rsv, gsh[c0 + 3], bsh[c0 + 3]));
    const float* w0 = &wsh[0 * 128 + c0];
    const float* w1 = &wsh[1 * 128 + c0];
    const float* w2 = &wsh[2 * 128 + c0];
    const float* w3 = &wsh[3 * 128 + c0];
    s0 += vx * w0[0] + vy * w0[1] + vz * w0[2] + vw * w0[3];
    s1 += vx * w1[0] + vy * w1[1] + vz * w1[2] + vw * w1[3];
    s2 += vx * w2[0] + vy * w2[1] + vz * w2[2] + vw * w2[3];
    s3 += vx * w3[0] + vy * w3[1] + vz * w3[2] + vw * w3[3];
  }
  red[pxl][q * 4 + 0] = s0; red[pxl][q * 4 + 1] = s1;
  red[pxl][q * 4 + 2] = s2; red[pxl][q * 4 + 3] = s3;
  __syncthreads();
  float val = red[pxl][0 * 4 + q] + red[pxl][1 * 4 + q] + red[pxl][2 * 4 + q] + red[pxl][3 * 4 + q] + bias[q];
  out[1 + (size_t)(n * 4 + q) * 9216 + px0 + pxl] = val;
}

extern "C" void kernel_launch(void* const* d_in, const int* in_sizes, int n_in,
                              void* d_out, int out_size, void* d_ws, size_t ws_size,
                              hipStream_t stream) {
  (void)in_sizes; (void)n_in; (void)out_size; (void)ws_size;
  const float* x     = (const float*)d_in[0];
  const float* e0_w  = (const float*)d_in[1];
  const float* e0_b  = (const float*)d_in[2];
  const float* e0_g  = (const float*)d_in[3];
  const float* e0_bt = (const float*)d_in[4];
  const float* e1_w  = (const float*)d_in[5];
  const float* e1_b  = (const float*)d_in[6];
  const float* e1_g  = (const float*)d_in[7];
  const float* e1_bt = (const float*)d_in[8];
  const float* pv_w  = (const float*)d_in[9];
  const float* pv_b  = (const float*)d_in[10];
  const float* emb   = (const float*)d_in[11];
  const float* d0_w  = (const float*)d_in[12];
  const float* d0_b  = (const float*)d_in[13];
  const float* d0_g  = (const float*)d_in[14];
  const float* d0_bt = (const float*)d_in[15];
  const float* d1_w  = (const float*)d_in[16];
  const float* d1_b  = (const float*)d_in[17];
  const float* d1_g  = (const float*)d_in[18];
  const float* d1_bt = (const float*)d_in[19];
  const float* pj_w  = (const float*)d_in[20];
  const float* pj_b  = (const float*)d_in[21];
  const float* ro_w  = (const float*)d_in[22];
  const float* ro_b  = (const float*)d_in[23];
  float* out = (float*)d_out;
  float* ws = (float*)d_ws;

  float* stats  = ws;                       // 64
  float* counts = ws + 64;                  // 1024
  float* enorm  = ws + 1088;                // 1024
  float* pvq    = ws + 2112;                // 1152
  float2* ps_e0 = (float2*)(ws + 3264);
  float2* ps_e1 = (float2*)(ws + 76992);
  float2* ps_d0 = (float2*)(ws + 95424);
  float2* ps_d1 = (float2*)(ws + 107712);   // 8*384 pairs = 6144 floats (region 6976)
  float* enc1   = ws + 114688;                     // 4718592 fp32 NCHW (raw e0 out)
  float* latent = enc1 + (size_t)NB * C * HW;      // 1179648 fp32 NCHW (raw e1 out)
  float* zbuf   = latent + (size_t)NB * C * HWL;   // 1179648 fp32 NCHW
  float* hy     = zbuf + (size_t)NB * C * HWL;     // 4718592 fp32 (e1 4-slice partials; then h,y NHWC)
  u16* qb    = (u16*)(hy + (size_t)NB * C * HW);   // 1179648 bf16 NHWC
  u16* hb    = qb + (size_t)NB * C * HWL;          // 4718592 bf16 NHWC
  u16* skipb = hb + (size_t)NB * C * HW;           // 4718592 bf16 NHWC
  u16* A1    = skipb + (size_t)NB * C * HW;        // 294912
  u16* A0    = A1 + 294912;                        // 147456
  u16* Apj   = A0 + 147456;                        // 16384
  float4* embp = (float4*)(Apj + 16384 + 64);      // 32768 float4
  // gnpad (20.07 MB) aliases qb+hb+skipb (21.2 MB); liveness: gn_pad -> e1s,
  // then k_vq/proj_m/gn_nhwc_bf overwrite. Keeps ws at the proven ~70 MB.
  float* gnpad = (float*)qb;

  k_pack_all<<<1925, 256, 0, stream>>>(d1_w, d0_w, pj_w, emb, A1, A0, Apj, embp, enorm, counts);

  k_conv_e0t<<<3072, 256, 0, stream>>>(x, e0_w, e0_b, enc1, ps_e0);
  k_red16<<<8, 256, 0, stream>>>(ps_e0, stats + 0, 384);
  k_gn_pad<<<512 * 9800 / 256, 256, 0, stream>>>(enc1, stats + 0, e0_g, e0_bt, gnpad);
  k_conv_e1s<<<768, 256, 0, stream>>>(gnpad, e1_w, hy);
  k_e1comb<<<NB * C * HWL / 256, 256, 0, stream>>>(hy, e1_b, latent, ps_e1);
  k_red16<<<8, 256, 0, stream>>>(ps_e1, stats + 16, 576);
  k_pv<<<288, 256, 0, stream>>>(latent, pv_w, pv_b, stats + 16, e1_g, e1_bt, zbuf);
  k_vq<<<ROWS / 8, 256, 0, stream>>>(zbuf, embp, emb, enorm, qb, counts, pvq);
  k_finalize<<<1, 256, 0, stream>>>(counts, pvq, out);

  k_proj_m<<<NB * 96, 256, 0, stream>>>(enc1, Apj, pj_b, stats + 0, e0_g, e0_bt, skipb);
  k_convt_d0m<<<NB * 96 * 2, 256, 0, stream>>>(qb, A0, d0_b, hy, ps_d0);
  k_red16<<<8, 256, 0, stream>>>(ps_d0, stats + 32, 384);
  k_gn_nhwc_bf<<<NB * C * HW / 256, 256, 0, stream>>>(hy, hb, stats + 32, d0_g, d0_bt);
  k_conv_d1m<<<NB * 96 * 2, 256, 0, stream>>>(hb, skipb, A1, d1_b, hy, ps_d1);
  k_red16<<<8, 256, 0, stream>>>(ps_d1, stats + 48, 384);
  k_ro<<<NB * 144, 256, 0, stream>>>(hy, ro_w, ro_b, stats + 48, d1_g, d1_bt, out);
}